// Round 7
// baseline (599.430 us; speedup 1.0000x reference)
//
#include <hip/hip_runtime.h>
#include <math.h>

#define NN0 20000
#define NN1 60000
#define NN2 40000
#define CC 256
#define OUTD 64
#define BB 8

// key space: L0 = row*2+slot in [0,40000); L1 = 40000+row*3+slot; L2 = 220000+row*2+slot
#define KB_L0 0
#define KB_L1 40000
#define KB_L2 220000
#define CTOT  300288      // padded key space bound (max key read = 300000)
#define ECAP  1300000

// radix partition params
#define NBUK  256
#define KPB   1174        // NBUK*KPB = 300544 >= 300001
#define SCAP  12288       // per-bucket staging capacity (worst mean ~8.2K, sigma ~90)
#define ACHUNK 4096

// X tiling (128-row tiles): x0 157, x1 469, x2 313 -> 939 tiles
#define XT0 0
#define XT1 157
#define XT2 626
#define XTTOT 939

typedef __bf16 bf16x8 __attribute__((ext_vector_type(8)));
typedef __bf16 bf16x4 __attribute__((ext_vector_type(4)));
typedef float  f32x4  __attribute__((ext_vector_type(4)));

__device__ __forceinline__ void glds16(const __bf16* g, __bf16* l) {
    __builtin_amdgcn_global_load_lds(
        (const __attribute__((address_space(1))) void*)g,
        (__attribute__((address_space(3))) void*)l, 16, 0, 0);
}

// ---------------------------------------------------------------------------
__global__ void zero_kernel(float4* __restrict__ p, long n4) {
    long i = (long)blockIdx.x * blockDim.x + threadIdx.x;
    long stride = (long)gridDim.x * blockDim.x;
    for (; i < n4; i += stride) p[i] = make_float4(0.f, 0.f, 0.f, 0.f);
}

// ---------------------------------------------------------------------------
struct WTab { const float* w[7]; };

// old-path: W (k-major fp32) -> Wt (n-major bf16)
__global__ void convert_w_old(WTab wt, __bf16* __restrict__ Wt) {
    int b = blockIdx.x;            // 7*256
    int w = b >> 8, n = b & 255;
    int k = threadIdx.x;
    Wt[((size_t)w * 256 + n) * 256 + k] = (__bf16)wt.w[w][k * 256 + n];
}

// new-path: W -> staging-tiled [(w*2+cb)*32+g][n] 16B granules
__global__ __launch_bounds__(256) void convert_w_tiled(WTab wt, __bf16* __restrict__ WtT) {
    int idx = blockIdx.x * 256 + threadIdx.x;   // 57344 slots
    int w = idx >> 13;
    int rem = idx & 8191;
    int cb = rem >> 12;
    int rem2 = rem & 4095;
    int g = rem2 >> 7, n = rem2 & 127;
    const float* W = wt.w[w];
    int col = cb * 128 + n;
    bf16x8 pk;
#pragma unroll
    for (int j = 0; j < 8; ++j) pk[j] = (__bf16)W[(g * 8 + j) * CC + col];
    *(bf16x8*)(WtT + (size_t)idx * 8) = pk;
}

// new-path: X fp32 -> staging-tiled bf16 [tile][g][m], zero-padded tail rows.
// One block per (tile, cb): coalesced float4 reads -> XOR-swizzled LDS
// (bank-conflict-free, measured 0 in r4) -> coalesced 16B granule writes.
struct XcvtTab { const float* src[3]; int tstart[4]; int nrows[3]; };
__global__ __launch_bounds__(256) void convert_x_tiled(XcvtTab xt, __bf16* __restrict__ XbT) {
    __shared__ __bf16 ls[8192];   // 16 KB: one 64-col block (8 gl x 128 r x 16B)
    const int b = blockIdx.x;
    const int tile = b >> 2, cb = b & 3;
    int s = (tile >= xt.tstart[1] ? 1 : 0) + (tile >= xt.tstart[2] ? 1 : 0);
    const float* src = xt.src[s];
    const int row0 = (tile - xt.tstart[s]) * 128;
    const int nrows = xt.nrows[s];
    __bf16* dst = XbT + ((size_t)tile * 4096 + (size_t)cb * 1024) * 8;
    const int t = threadIdx.x;
    const int rr = t >> 4;            // 0..15
    const int c4 = (t & 15) * 4;      // col offset within 64-col block
    const int gl = c4 >> 3;           // granule-group 0..7
    const int sub = c4 & 7;           // 0 or 4
    const int xorbits = (gl & 7) << 4;
    // phase A: coalesced read + convert -> swizzled LDS
#pragma unroll
    for (int jj = 0; jj < 8; ++jj) {
        int r = jj * 16 + rr;
        int gr = row0 + r;
        float4 f;
        if (gr < nrows) f = *(const float4*)(src + (size_t)gr * CC + cb * 64 + c4);
        else            f = make_float4(0.f, 0.f, 0.f, 0.f);
        bf16x4 pk;
        pk[0] = (__bf16)f.x; pk[1] = (__bf16)f.y; pk[2] = (__bf16)f.z; pk[3] = (__bf16)f.w;
        int byteoff = (gl * 2048 + r * 16 + sub * 2) ^ xorbits;
        *(bf16x4*)((char*)ls + byteoff) = pk;
    }
    __syncthreads();
    // phase B: swizzled LDS read -> coalesced granule write (4 KB/wave-iter)
#pragma unroll
    for (int j = 0; j < 4; ++j) {
        int sidx = j * 256 + t;       // granule index within this cb region
        int byteoff = (sidx * 16) ^ (((sidx >> 7) & 7) << 4);
        *(bf16x8*)(dst + (size_t)sidx * 8) = *(bf16x8*)((char*)ls + byteoff);
    }
}

// ---------------------------------------------------------------------------
struct GemmJob { const float* X; int xTile; int wIdx; int rowBase; int M; };
struct GemmTab { GemmJob j[3]; };

// new-path GEMM: bf16 tiled inputs, global_load_lds staging (m97 structure).
// Epilogue: LDS-staged coalesced output (64 scalar 2B stores -> 8x 16B stores).
__global__ __launch_bounds__(256) void gemm_glds(GemmTab tab,
                                                 const __bf16* __restrict__ WtT,
                                                 const __bf16* __restrict__ XbT,
                                                 __bf16* __restrict__ T) {
    const GemmJob job = tab.j[blockIdx.z];
    const int row0 = blockIdx.x * 128;
    if (row0 >= job.M) return;
    const int M = job.M;

    __shared__ __bf16 smem[8192];      // 16 KB: Als(8K) | Bls(8K); epilogue reuses all
    __bf16* Als = smem;
    __bf16* Bls = smem + 4096;
    const int t = threadIdx.x;
    const int col0 = blockIdx.y * 128;
    const int lane = t & 63, wave = t >> 6;
    const int q = lane >> 4, lm = lane & 15;
    const int wm = (wave & 1) * 64, wn = (wave >> 1) * 64;

    f32x4 acc[4][4];
    const f32x4 z = {0.f, 0.f, 0.f, 0.f};
#pragma unroll
    for (int i = 0; i < 4; ++i)
#pragma unroll
        for (int j = 0; j < 4; ++j) acc[i][j] = z;

    // staging: per wave two issues, slots sb = wave*128 + s*64 (slot = g*128+m)
    const int sb0 = wave * 128, sb1 = sb0 + 64;
    const int g0 = sb0 >> 7, m0 = (sb0 & 127) + lane;
    const int g1 = sb1 >> 7, m1 = (sb1 & 127) + lane;
    const __bf16* aSrc0 = XbT + (((size_t)(job.xTile + blockIdx.x) * 32 + g0) * 128 + m0) * 8;
    const __bf16* aSrc1 = XbT + (((size_t)(job.xTile + blockIdx.x) * 32 + g1) * 128 + m1) * 8;
    const __bf16* bSrc0 = WtT + (((size_t)(job.wIdx * 2 + blockIdx.y) * 32 + g0) * 128 + m0) * 8;
    const __bf16* bSrc1 = WtT + (((size_t)(job.wIdx * 2 + blockIdx.y) * 32 + g1) * 128 + m1) * 8;
    __bf16* aDst0 = &Als[(sb0 + lane) * 8];
    __bf16* aDst1 = &Als[(sb1 + lane) * 8];
    __bf16* bDst0 = &Bls[(sb0 + lane) * 8];
    __bf16* bDst1 = &Bls[(sb1 + lane) * 8];

    for (int it = 0; it < 8; ++it) {
        glds16(aSrc0, aDst0); glds16(aSrc1, aDst1);
        glds16(bSrc0, bDst0); glds16(bSrc1, bDst1);
        aSrc0 += 4096; aSrc1 += 4096; bSrc0 += 4096; bSrc1 += 4096;
        __syncthreads();
        bf16x8 af[4], bfr[4];
#pragma unroll
        for (int i = 0; i < 4; ++i)
            af[i] = *(bf16x8*)&Als[(q * 128 + wm + 16 * i + lm) * 8];
#pragma unroll
        for (int j = 0; j < 4; ++j)
            bfr[j] = *(bf16x8*)&Bls[(q * 128 + wn + 16 * j + lm) * 8];
#pragma unroll
        for (int i = 0; i < 4; ++i)
#pragma unroll
            for (int j = 0; j < 4; ++j)
                acc[i][j] = __builtin_amdgcn_mfma_f32_16x16x32_bf16(af[i], bfr[j], acc[i][j], 0, 0, 0);
        __syncthreads();
    }

    // ---- epilogue: acc -> LDS (bf16, swizzled) -> coalesced 16B stores ----
    const int hsel = wave >> 1;        // this wave's col-half (wn = hsel*64)
#pragma unroll
    for (int h = 0; h < 2; ++h) {
        if (hsel == h) {
#pragma unroll
            for (int i = 0; i < 4; ++i)
#pragma unroll
                for (int j = 0; j < 4; ++j)
#pragma unroll
                    for (int r = 0; r < 4; ++r) {
                        int row = wm + 16 * i + q * 4 + r;
                        int colw = 16 * j + lm;
                        smem[row * 64 + (colw ^ ((row & 7) << 3))] = (__bf16)acc[i][j][r];
                    }
        }
        __syncthreads();
#pragma unroll
        for (int it2 = 0; it2 < 4; ++it2) {
            int idx = it2 * 256 + t;
            int row = idx >> 3, c8 = (idx & 7) * 8;
            int grow = row0 + row;
            if (grow < M) {
                bf16x8 v = *(bf16x8*)&smem[row * 64 + (c8 ^ ((row & 7) << 3))];
                *(bf16x8*)(T + (size_t)(job.rowBase + grow) * CC + col0 + h * 64 + c8) = v;
            }
        }
        __syncthreads();
    }
}

// old-path GEMM (round-7): fp32 X staging with on-the-fly pack
__global__ __launch_bounds__(256) void gemm_level(GemmTab tab,
                                                  const __bf16* __restrict__ WtAll,
                                                  __bf16* __restrict__ T) {
    const GemmJob job = tab.j[blockIdx.z];
    const int row0 = blockIdx.x * 128;
    if (row0 >= job.M) return;
    const int M = job.M;
    const float* __restrict__ X = job.X;
    const __bf16* __restrict__ Wt = WtAll + (size_t)job.wIdx * CC * CC;

    __shared__ __bf16 Als[4096];
    __shared__ __bf16 Bls[4096];
    const int t = threadIdx.x;
    const int col0 = blockIdx.y * 128;
    const int lane = t & 63, wave = t >> 6;
    const int q = lane >> 4, lm = lane & 15;
    const int wm = (wave & 1) * 64, wn = (wave >> 1) * 64;

    f32x4 acc[4][4];
    const f32x4 z = {0.f, 0.f, 0.f, 0.f};
#pragma unroll
    for (int i = 0; i < 4; ++i)
#pragma unroll
        for (int j = 0; j < 4; ++j) acc[i][j] = z;

    const int g0 = t >> 7, ms = t & 127;
    int arow = row0 + ms; if (arow > M - 1) arow = M - 1;
    const float*  ap = X  + (size_t)arow * CC;
    const __bf16* bp = Wt + (size_t)(col0 + ms) * CC;

    for (int kk = 0; kk < CC; kk += 32) {
#pragma unroll
        for (int s = 0; s < 2; ++s) {
            int g = g0 + s * 2;
            float4 f0 = *(const float4*)(ap + kk + g * 8);
            float4 f1 = *(const float4*)(ap + kk + g * 8 + 4);
            bf16x8 pk;
            pk[0] = (__bf16)f0.x; pk[1] = (__bf16)f0.y; pk[2] = (__bf16)f0.z; pk[3] = (__bf16)f0.w;
            pk[4] = (__bf16)f1.x; pk[5] = (__bf16)f1.y; pk[6] = (__bf16)f1.z; pk[7] = (__bf16)f1.w;
            *(bf16x8*)&Als[(g * 128 + ms) * 8] = pk;
            *(bf16x8*)&Bls[(g * 128 + ms) * 8] = *(const bf16x8*)(bp + kk + g * 8);
        }
        __syncthreads();
        bf16x8 af[4], bfr[4];
#pragma unroll
        for (int i = 0; i < 4; ++i)
            af[i] = *(bf16x8*)&Als[(q * 128 + wm + 16 * i + lm) * 8];
#pragma unroll
        for (int j = 0; j < 4; ++j)
            bfr[j] = *(bf16x8*)&Bls[(q * 128 + wn + 16 * j + lm) * 8];
#pragma unroll
        for (int i = 0; i < 4; ++i)
#pragma unroll
            for (int j = 0; j < 4; ++j)
                acc[i][j] = __builtin_amdgcn_mfma_f32_16x16x32_bf16(af[i], bfr[j], acc[i][j], 0, 0, 0);
        __syncthreads();
    }
#pragma unroll
    for (int i = 0; i < 4; ++i) {
        int gr0 = row0 + wm + 16 * i + q * 4;
#pragma unroll
        for (int r = 0; r < 4; ++r) {
            int grow = gr0 + r;
            if (grow < M) {
                __bf16* dst = T + (size_t)(job.rowBase + grow) * CC + col0 + wn + lm;
#pragma unroll
                for (int j = 0; j < 4; ++j) dst[16 * j] = (__bf16)acc[i][j][r];
            }
        }
    }
}

// ---------------------------------------------------------------------------
// two-phase CSR build: bucket partition (coalesced runs) + per-bucket scatter
// ---------------------------------------------------------------------------
struct SrcTab {
    const int*   rows[8];
    const int*   cols[8];
    const float* vals[8];
    int pre[9];
    int kbase[8];
    int mulS[8];
    int slot[8];
    int tbase[8];
};

// phase A: bin 4096-entry chunks into NBUK key-range buckets.
// entry packed: .x = (keyLocal<<17)|col  (keyLocal<1174 fits 11b, col<120000 fits 17b)
__global__ __launch_bounds__(256) void bin_partition(SrcTab st, int* __restrict__ bucketCursor,
                                                     int2* __restrict__ stage, int total) {
    __shared__ int hist[NBUK];
    __shared__ int bbase[NBUK];
    const int t = threadIdx.x;
    hist[t] = 0;
    __syncthreads();
    const int base0 = blockIdx.x * ACHUNK;
    int2 ent[16];
    int  meta[16];   // (bucket<<16)|rank ; -1 = invalid
#pragma unroll
    for (int k = 0; k < 16; ++k) {
        int i = base0 + k * 256 + t;
        if (i < total) {
            int s = 0;
            while (i >= st.pre[s + 1]) ++s;
            int j = i - st.pre[s];
            int key = st.kbase[s] + st.rows[s][j] * st.mulS[s] + st.slot[s];
            int bkt = key / KPB;
            int kl = key - bkt * KPB;
            ent[k] = make_int2((kl << 17) | (st.cols[s][j] + st.tbase[s]),
                               __float_as_int(st.vals[s][j]));
            int r = atomicAdd(&hist[bkt], 1);
            meta[k] = (bkt << 16) | r;
        } else {
            meta[k] = -1;
        }
    }
    __syncthreads();
    // one global reserve per bucket: block's entries form contiguous runs
    bbase[t] = atomicAdd(&bucketCursor[t], hist[t]);
    __syncthreads();
#pragma unroll
    for (int k = 0; k < 16; ++k) {
        if (meta[k] >= 0) {
            int bkt = meta[k] >> 16, r = meta[k] & 0xFFFF;
            stage[(size_t)bkt * SCAP + bbase[bkt] + r] = ent[k];
        }
    }
}

// exclusive scan over NBUK bucket counts (1 block)
__global__ __launch_bounds__(256) void scan_nb(const int* __restrict__ cnts,
                                               int* __restrict__ bbase) {
    __shared__ int sm[256];
    int t = threadIdx.x;
    int v = cnts[t];
    sm[t] = v;
    __syncthreads();
    for (int d = 1; d < 256; d <<= 1) {
        int x = (t >= d) ? sm[t - d] : 0;
        __syncthreads();
        sm[t] += x;
        __syncthreads();
    }
    bbase[t] = sm[t] - v;
}

// phase B: per-bucket local histogram + scan -> rstart; scatter into the
// bucket's contiguous epair region (block-local lines, ~1x amplification)
__global__ __launch_bounds__(256) void bin_scatter(const int2* __restrict__ stage,
                                                   const int* __restrict__ bucketCnt,
                                                   const int* __restrict__ bucketBase,
                                                   int* __restrict__ rstart,
                                                   int2* __restrict__ epair) {
    const int b = blockIdx.x;
    const int n = bucketCnt[b];
    const int base = bucketBase[b];
    const int t = threadIdx.x;
    __shared__ int cur[KPB];     // counts, then cursors
    __shared__ int tsum[256];
    for (int k = t; k < KPB; k += 256) cur[k] = 0;
    __syncthreads();
    const int2* sp = stage + (size_t)b * SCAP;
    for (int i = t; i < n; i += 256)
        atomicAdd(&cur[sp[i].x >> 17], 1);
    __syncthreads();
    // exclusive scan over KPB counts: thread t owns keys [t*5, t*5+5)
    int loc[5];
    int s = 0;
#pragma unroll
    for (int k = 0; k < 5; ++k) {
        int kk = t * 5 + k;
        int v = (kk < KPB) ? cur[kk] : 0;
        loc[k] = s;
        s += v;
    }
    tsum[t] = s;
    __syncthreads();
    for (int d = 1; d < 256; d <<= 1) {
        int x = (t >= d) ? tsum[t - d] : 0;
        __syncthreads();
        tsum[t] += x;
        __syncthreads();
    }
    int texcl = tsum[t] - s;
#pragma unroll
    for (int k = 0; k < 5; ++k) {
        int kk = t * 5 + k;
        if (kk < KPB) {
            int st = base + texcl + loc[k];
            int gk = b * KPB + kk;
            if (gk < CTOT) rstart[gk] = st;
            cur[kk] = st;
        }
    }
    __syncthreads();
    for (int i = t; i < n; i += 256) {
        int2 e = sp[i];
        int kl = e.x >> 17;
        int pos = atomicAdd(&cur[kl], 1);
        epair[pos] = make_int2(e.x & 0x1FFFF, e.y);
    }
}

// ---------------------------------------------------------------------------
// fused per-level SPMM, gather pipelined x8/x4/x1
// ---------------------------------------------------------------------------
__global__ __launch_bounds__(256) void spmm_level(const int2* __restrict__ epair,
                                                  const int* __restrict__ rstart,
                                                  const __bf16* __restrict__ T,
                                                  __bf16* __restrict__ acc,
                                                  int Kb, int S, int nrows) {
    int row = blockIdx.x * 4 + (threadIdx.x >> 6);
    if (row >= nrows) return;
    int l = threadIdx.x & 63;
    int s0 = rstart[Kb + row * S];
    int e = rstart[Kb + row * S + S];
    const unsigned short* Tb = (const unsigned short*)T + l * 4;
    float4 a0 = make_float4(0.f, 0.f, 0.f, 0.f);
    for (int base = s0; base < e; base += 64) {
        int j = base + l;
        int off = 0; float v = 0.f;
        if (j < e) { int2 ee = epair[j]; off = ee.x; v = __int_as_float(ee.y); }
        int lim = e - base; if (lim > 64) lim = 64;
        int i = 0;
        for (; i + 8 <= lim; i += 8) {
            int ob[8]; float vb[8]; uint2 u[8];
#pragma unroll
            for (int p = 0; p < 8; ++p) { ob[p] = __shfl(off, i + p, 64); vb[p] = __shfl(v, i + p, 64); }
#pragma unroll
            for (int p = 0; p < 8; ++p) u[p] = *(const uint2*)(Tb + (size_t)ob[p] * CC);
#pragma unroll
            for (int p = 0; p < 8; ++p) {
                a0.x += vb[p] * __uint_as_float(u[p].x << 16);
                a0.y += vb[p] * __uint_as_float(u[p].x & 0xFFFF0000u);
                a0.z += vb[p] * __uint_as_float(u[p].y << 16);
                a0.w += vb[p] * __uint_as_float(u[p].y & 0xFFFF0000u);
            }
        }
        for (; i + 4 <= lim; i += 4) {
            int ob[4]; float vb[4]; uint2 u[4];
#pragma unroll
            for (int p = 0; p < 4; ++p) { ob[p] = __shfl(off, i + p, 64); vb[p] = __shfl(v, i + p, 64); }
#pragma unroll
            for (int p = 0; p < 4; ++p) u[p] = *(const uint2*)(Tb + (size_t)ob[p] * CC);
#pragma unroll
            for (int p = 0; p < 4; ++p) {
                a0.x += vb[p] * __uint_as_float(u[p].x << 16);
                a0.y += vb[p] * __uint_as_float(u[p].x & 0xFFFF0000u);
                a0.z += vb[p] * __uint_as_float(u[p].y << 16);
                a0.w += vb[p] * __uint_as_float(u[p].y & 0xFFFF0000u);
            }
        }
        for (; i < lim; ++i) {
            int   ob = __shfl(off, i, 64);
            float vb = __shfl(v, i, 64);
            uint2 u = *(const uint2*)(Tb + (size_t)ob * CC);
            a0.x += vb * __uint_as_float(u.x << 16);
            a0.y += vb * __uint_as_float(u.x & 0xFFFF0000u);
            a0.z += vb * __uint_as_float(u.y << 16);
            a0.w += vb * __uint_as_float(u.y & 0xFFFF0000u);
        }
    }
    bf16x4 o;
    o[0] = (__bf16)a0.x; o[1] = (__bf16)a0.y; o[2] = (__bf16)a0.z; o[3] = (__bf16)a0.w;
    *(bf16x4*)(acc + (size_t)row * CC + l * 4) = o;
}

// ---------------------------------------------------------------------------
__global__ void seg_count_all(const int* __restrict__ s0, const int* __restrict__ s1,
                              const int* __restrict__ s2, int* __restrict__ cnt) {
    int i = blockIdx.x * 256 + threadIdx.x;
    int a = (i < NN0) ? s0[i] : -1;
    int b = (i < NN1) ? s1[i] : -1;
    int c = (i < NN2) ? s2[i] : -1;
#pragma unroll
    for (int v = 0; v < BB; ++v) {
        unsigned long long m0 = __ballot(a == v);
        unsigned long long m1 = __ballot(b == v);
        unsigned long long m2 = __ballot(c == v);
        if ((threadIdx.x & 63) == 0) {
            if (m0) atomicAdd(&cnt[v], (int)__popcll(m0));
            if (m1) atomicAdd(&cnt[8 + v], (int)__popcll(m1));
            if (m2) atomicAdd(&cnt[16 + v], (int)__popcll(m2));
        }
    }
}

__global__ __launch_bounds__(256) void pool_sigmoid(const __bf16* __restrict__ acc,
                                                    const int* __restrict__ seg,
                                                    float* __restrict__ poolh, int n) {
    const unsigned short* A = (const unsigned short*)acc;
    int c = threadIdx.x;
    int node0 = blockIdx.x * 64;
    int nend = min(node0 + 64, n);
    float run = 0.f;
    int curseg = seg[node0];
    for (int node = node0; node < nend; ++node) {
        int s = seg[node];
        float a = __uint_as_float((unsigned)A[(size_t)node * CC + c] << 16);
        float h = 1.f / (1.f + __expf(-a));
        if (s != curseg) {
            atomicAdd(&poolh[curseg * CC + c], run);
            run = 0.f; curseg = s;
        }
        run += h;
    }
    atomicAdd(&poolh[curseg * CC + c], run);
}

__global__ __launch_bounds__(64) void final_head(const float* __restrict__ ph0,
                                                 const float* __restrict__ ph1,
                                                 const float* __restrict__ ph2,
                                                 const int* __restrict__ c0,
                                                 const int* __restrict__ c1,
                                                 const int* __restrict__ c2,
                                                 const float* __restrict__ W0,
                                                 const float* __restrict__ W1,
                                                 const float* __restrict__ W2,
                                                 const float* __restrict__ b0,
                                                 const float* __restrict__ b1,
                                                 const float* __restrict__ b2,
                                                 float* __restrict__ out) {
    int s = blockIdx.x, o = threadIdx.x;
    float inv0 = 1.f / fmaxf((float)c0[s], 1.f);
    float inv1 = 1.f / fmaxf((float)c1[s], 1.f);
    float inv2 = 1.f / fmaxf((float)c2[s], 1.f);
    float a0 = 0.f, a1 = 0.f, a2 = 0.f;
    for (int k = 0; k < CC; ++k) {
        a0 += ph0[s * CC + k] * W0[k * OUTD + o];
        a1 += ph1[s * CC + k] * W1[k * OUTD + o];
        a2 += ph2[s * CC + k] * W2[k * OUTD + o];
    }
    out[s * OUTD + o] = (a0 * inv0 + b0[o] + a1 * inv1 + b1[o] + a2 * inv2 + b2[o]) * (1.f / 3.f);
}

// ---------------------------------------------------------------------------
extern "C" void kernel_launch(void* const* d_in, const int* in_sizes, int n_in,
                              void* d_out, int out_size, void* d_ws, size_t ws_size,
                              hipStream_t stream) {
    const float* x0 = (const float*)d_in[0];
    const float* x1 = (const float*)d_in[1];
    const float* x2 = (const float*)d_in[2];
    const int* belong0 = (const int*)d_in[27];
    const int* belong1 = (const int*)d_in[28];
    const int* belong2 = (const int*)d_in[29];

    // ---- workspace layout (bytes) ----
    char* w = (char*)d_ws;
    __bf16* T    = (__bf16*)w;  w += (size_t)120000 * CC * 2;  // 61.44 MB
    __bf16* accb = (__bf16*)w;  w += (size_t)NN1 * CC * 2;     // 30.72 MB
    __bf16* Wt   = (__bf16*)w;  w += (size_t)7 * CC * CC * 2;  // both layouts fit
    int2*   epair= (int2*)w;    w += (size_t)ECAP * 8;
    int*  bucketCursor = (int*)w; w += NBUK * 4;               // zero-region start
    float*  poolh= (float*)w;   w += 3 * BB * CC * 4;
    int*    segc = (int*)w;     w += 32 * 4;                   // zero-region end
    int*  bucketBase = (int*)w; w += NBUK * 4;
    int*    rstart=(int*)w;     w += (size_t)CTOT * 4;
    __bf16* XbT  = (__bf16*)w;  w += (size_t)XTTOT * 4096 * 16; // 61.54 MB (new path only)
    size_t required_new = (size_t)(w - (char*)d_ws);
    int* cnt0 = segc, *cnt1 = segc + 8, *cnt2 = segc + 16;
    const bool use_glds = (ws_size >= required_new);

    // staging buffer for the radix partition aliases T (written only by the
    // GEMMs, which launch after bin_scatter completes): 256*12288*8 = 25.2 MB
    int2* stage = (int2*)T;

    // ---- source table: order adj0, inc1 | inc1t, adjd1, adju1, inc2 | inc2t, adjd2
    const int bases[8] = {15, 3, 9, 21, 18, 6, 12, 24};
    const int kbase[8] = {KB_L0, KB_L0, KB_L1, KB_L1, KB_L1, KB_L1, KB_L2, KB_L2};
    const int mulS [8] = {2, 2, 3, 3, 3, 3, 2, 2};
    const int slot [8] = {0, 1, 0, 1, 1, 2, 0, 1};
    const int tbase[8] = {0, 20000, 0, 20000, 20000, 80000, 0, 60000};
    SrcTab st;
    int run = 0;
    for (int s = 0; s < 8; ++s) {
        st.rows[s] = (const int*)d_in[bases[s]];
        st.cols[s] = (const int*)d_in[bases[s] + 1];
        st.vals[s] = (const float*)d_in[bases[s] + 2];
        st.kbase[s] = kbase[s]; st.mulS[s] = mulS[s];
        st.slot[s] = slot[s];   st.tbase[s] = tbase[s];
        st.pre[s] = run;
        run += in_sizes[bases[s]];
    }
    st.pre[8] = run;
    const int total = run;

    WTab wt;
    for (int i = 0; i < 7; ++i) wt.w[i] = (const float*)d_in[30 + i];

    // ---- CSR build (two-phase) + weight/X convert + seg counts ----
    zero_kernel<<<8, 256, 0, stream>>>((float4*)bucketCursor,
                                       (NBUK * 4 + 3 * BB * CC * 4 + 128) / 16);
    bin_partition<<<(total + ACHUNK - 1) / ACHUNK, 256, 0, stream>>>(st, bucketCursor, stage, total);
    if (use_glds) {
        convert_w_tiled<<<224, 256, 0, stream>>>(wt, Wt);
        XcvtTab xt;
        xt.src[0] = x0; xt.src[1] = x1; xt.src[2] = x2;
        xt.tstart[0] = XT0; xt.tstart[1] = XT1; xt.tstart[2] = XT2; xt.tstart[3] = XTTOT;
        xt.nrows[0] = NN0; xt.nrows[1] = NN1; xt.nrows[2] = NN2;
        convert_x_tiled<<<XTTOT * 4, 256, 0, stream>>>(xt, XbT);
    } else {
        convert_w_old<<<7 * 256, 256, 0, stream>>>(wt, Wt);
    }
    seg_count_all<<<(NN1 + 255) / 256, 256, 0, stream>>>(belong0, belong1, belong2, segc);
    scan_nb<<<1, 256, 0, stream>>>(bucketCursor, bucketBase);
    bin_scatter<<<NBUK, 256, 0, stream>>>(stage, bucketCursor, bucketBase, rstart, epair);

    auto launch_gemm = [&](GemmTab& g, int njobs) {
        dim3 grid((NN1 + 127) / 128, 2, njobs);
        if (use_glds) gemm_glds<<<grid, 256, 0, stream>>>(g, Wt, XbT, T);
        else          gemm_level<<<grid, 256, 0, stream>>>(g, Wt, T);
    };

    // ---- level 0: T = [x0@W00 (20k) | x1@W10 (60k)] ----
    {
        GemmTab g;
        g.j[0] = {x0, XT0, 0, 0, NN0};
        g.j[1] = {x1, XT1, 1, 20000, NN1};
        launch_gemm(g, 2);
        spmm_level<<<(NN0 + 3) / 4, 256, 0, stream>>>(epair, rstart, T, accb, KB_L0, 2, NN0);
        pool_sigmoid<<<(NN0 + 63) / 64, 256, 0, stream>>>(accb, belong0, poolh, NN0);
    }
    // ---- level 1: T = [x0@W01 (20k) | x1@W11 (60k) | x2@W21 (40k)] ----
    {
        GemmTab g;
        g.j[0] = {x0, XT0, 2, 0, NN0};
        g.j[1] = {x1, XT1, 3, 20000, NN1};
        g.j[2] = {x2, XT2, 4, 80000, NN2};
        launch_gemm(g, 3);
        spmm_level<<<(NN1 + 3) / 4, 256, 0, stream>>>(epair, rstart, T, accb, KB_L1, 3, NN1);
        pool_sigmoid<<<(NN1 + 63) / 64, 256, 0, stream>>>(accb, belong1, poolh + BB * CC, NN1);
    }
    // ---- level 2: T = [x1@W12 (60k) | x2@W22 (40k)] ----
    {
        GemmTab g;
        g.j[0] = {x1, XT1, 5, 0, NN1};
        g.j[1] = {x2, XT2, 6, 60000, NN2};
        launch_gemm(g, 2);
        spmm_level<<<(NN2 + 3) / 4, 256, 0, stream>>>(epair, rstart, T, accb, KB_L2, 2, NN2);
        pool_sigmoid<<<(NN2 + 63) / 64, 256, 0, stream>>>(accb, belong2, poolh + 2 * BB * CC, NN2);
    }

    // ---- combine ----
    final_head<<<BB, 64, 0, stream>>>(poolh, poolh + BB * CC, poolh + 2 * BB * CC,
                                      cnt0, cnt1, cnt2,
                                      (const float*)d_in[37], (const float*)d_in[38],
                                      (const float*)d_in[39], (const float*)d_in[40],
                                      (const float*)d_in[41], (const float*)d_in[42],
                                      (float*)d_out);
}

// Round 8
// 560.233 us; speedup vs baseline: 1.0700x; 1.0700x over previous
//
#include <hip/hip_runtime.h>
#include <math.h>

#define NN0 20000
#define NN1 60000
#define NN2 40000
#define CC 256
#define OUTD 64
#define BB 8

// key space: L0 = row*2+slot in [0,40000); L1 = 40000+row*3+slot; L2 = 220000+row*2+slot
#define KB_L0 0
#define KB_L1 40000
#define KB_L2 220000
#define CTOT  300288
#define ECAP  1300000

// radix partition params
#define NBUK  256
#define KPB   1174        // NBUK*KPB = 300544 >= 300001
#define SCAP  12288       // per-bucket staging cap (worst mean ~8.2K, sigma ~90)
#define ACHUNK 4096

// X tiling (128-row tiles): x0 157, x1 469, x2 313 -> 939 tiles
#define XT0 0
#define XT1 157
#define XT2 626
#define XTTOT 939
#define GXB 469           // (NN1+127)/128

typedef __bf16 bf16x8 __attribute__((ext_vector_type(8)));
typedef __bf16 bf16x4 __attribute__((ext_vector_type(4)));
typedef float  f32x4  __attribute__((ext_vector_type(4)));

__device__ __forceinline__ void glds16(const __bf16* g, __bf16* l) {
    __builtin_amdgcn_global_load_lds(
        (const __attribute__((address_space(1))) void*)g,
        (__attribute__((address_space(3))) void*)l, 16, 0, 0);
}

// ---------------------------------------------------------------------------
__global__ void zero_kernel(float4* __restrict__ p, long n4) {
    long i = (long)blockIdx.x * blockDim.x + threadIdx.x;
    long stride = (long)gridDim.x * blockDim.x;
    for (; i < n4; i += stride) p[i] = make_float4(0.f, 0.f, 0.f, 0.f);
}

// ---------------------------------------------------------------------------
struct WTab { const float* w[7]; };
struct XcvtTab { const float* src[3]; int tstart[4]; int nrows[3]; };

// ---- device cores (bodies identical to round-4 kernels) -------------------

// convert X tile-block b in [0, XTTOT*4): coalesced f32 reads -> XOR-swizzled
// LDS (0-conflict, measured r4) -> coalesced 16B granule writes
__device__ __forceinline__ void convert_x_core(const XcvtTab& xt, __bf16* __restrict__ XbT,
                                               char* smemraw, int b) {
    __bf16* ls = (__bf16*)smemraw;   // 16 KB
    const int tile = b >> 2, cb = b & 3;
    int s = (tile >= xt.tstart[1] ? 1 : 0) + (tile >= xt.tstart[2] ? 1 : 0);
    const float* src = xt.src[s];
    const int row0 = (tile - xt.tstart[s]) * 128;
    const int nrows = xt.nrows[s];
    __bf16* dst = XbT + ((size_t)tile * 4096 + (size_t)cb * 1024) * 8;
    const int t = threadIdx.x;
    const int rr = t >> 4;
    const int c4 = (t & 15) * 4;
    const int gl = c4 >> 3;
    const int sub = c4 & 7;
    const int xorbits = (gl & 7) << 4;
#pragma unroll
    for (int jj = 0; jj < 8; ++jj) {
        int r = jj * 16 + rr;
        int gr = row0 + r;
        float4 f;
        if (gr < nrows) f = *(const float4*)(src + (size_t)gr * CC + cb * 64 + c4);
        else            f = make_float4(0.f, 0.f, 0.f, 0.f);
        bf16x4 pk;
        pk[0] = (__bf16)f.x; pk[1] = (__bf16)f.y; pk[2] = (__bf16)f.z; pk[3] = (__bf16)f.w;
        int byteoff = (gl * 2048 + r * 16 + sub * 2) ^ xorbits;
        *(bf16x4*)((char*)ls + byteoff) = pk;
    }
    __syncthreads();
#pragma unroll
    for (int j = 0; j < 4; ++j) {
        int sidx = j * 256 + t;
        int byteoff = (sidx * 16) ^ (((sidx >> 7) & 7) << 4);
        *(bf16x8*)(dst + (size_t)sidx * 8) = *(bf16x8*)((char*)ls + byteoff);
    }
}

__device__ __forceinline__ void convert_w_core(const WTab& wt, __bf16* __restrict__ WtT, int wb) {
    int idx = wb * 256 + threadIdx.x;   // 57344 slots
    int w = idx >> 13;
    int rem = idx & 8191;
    int cb = rem >> 12;
    int rem2 = rem & 4095;
    int g = rem2 >> 7, n = rem2 & 127;
    const float* W = wt.w[w];
    int col = cb * 128 + n;
    bf16x8 pk;
#pragma unroll
    for (int j = 0; j < 8; ++j) pk[j] = (__bf16)W[(g * 8 + j) * CC + col];
    *(bf16x8*)(WtT + (size_t)idx * 8) = pk;
}

__device__ __forceinline__ void seg_core(const int* s0, const int* s1, const int* s2,
                                         int* cnt, int blk) {
    int i = blk * 256 + threadIdx.x;
    int a = (i < NN0) ? s0[i] : -1;
    int b = (i < NN1) ? s1[i] : -1;
    int c = (i < NN2) ? s2[i] : -1;
#pragma unroll
    for (int v = 0; v < BB; ++v) {
        unsigned long long m0 = __ballot(a == v);
        unsigned long long m1 = __ballot(b == v);
        unsigned long long m2 = __ballot(c == v);
        if ((threadIdx.x & 63) == 0) {
            if (m0) atomicAdd(&cnt[v], (int)__popcll(m0));
            if (m1) atomicAdd(&cnt[8 + v], (int)__popcll(m1));
            if (m2) atomicAdd(&cnt[16 + v], (int)__popcll(m2));
        }
    }
}

struct SrcTab {
    const int*   rows[8];
    const int*   cols[8];
    const float* vals[8];
    int pre[9];
    int kbase[8];
    int mulS[8];
    int slot[8];
    int tbase[8];
};

__device__ __forceinline__ void partition_core(const SrcTab& st, int* __restrict__ bucketCursor,
                                               int2* __restrict__ stage, int total, int chunk) {
    __shared__ int hist[NBUK];
    __shared__ int bbase[NBUK];
    const int t = threadIdx.x;
    hist[t] = 0;
    __syncthreads();
    const int base0 = chunk * ACHUNK;
    int2 ent[16];
    int  meta[16];
#pragma unroll
    for (int k = 0; k < 16; ++k) {
        int i = base0 + k * 256 + t;
        if (i < total) {
            int s = 0;
            while (i >= st.pre[s + 1]) ++s;
            int j = i - st.pre[s];
            int key = st.kbase[s] + st.rows[s][j] * st.mulS[s] + st.slot[s];
            int bkt = key / KPB;
            int kl = key - bkt * KPB;
            ent[k] = make_int2((kl << 17) | (st.cols[s][j] + st.tbase[s]),
                               __float_as_int(st.vals[s][j]));
            int r = atomicAdd(&hist[bkt], 1);
            meta[k] = (bkt << 16) | r;
        } else {
            meta[k] = -1;
        }
    }
    __syncthreads();
    bbase[t] = atomicAdd(&bucketCursor[t], hist[t]);
    __syncthreads();
#pragma unroll
    for (int k = 0; k < 16; ++k) {
        if (meta[k] >= 0) {
            int bkt = meta[k] >> 16, r = meta[k] & 0xFFFF;
            stage[(size_t)bkt * SCAP + bbase[bkt] + r] = ent[k];
        }
    }
}

// per-bucket scatter with INLINED bucket-base scan (replaces scan_nb)
__device__ __forceinline__ void scatter_core(const int2* __restrict__ stage,
                                             const int* __restrict__ cnts,
                                             int* __restrict__ rstart,
                                             int2* __restrict__ epair,
                                             char* smemraw, int b) {
    int* cur  = (int*)smemraw;          // KPB
    int* tsum = cur + KPB;              // 256
    int* sbuf = tsum + 256;             // 256   (total 6744 B < 16 KB)
    const int t = threadIdx.x;
    for (int k = t; k < KPB; k += 256) cur[k] = 0;
    sbuf[t] = cnts[t];
    __syncthreads();
    for (int d = 1; d < 256; d <<= 1) {
        int x = (t >= d) ? sbuf[t - d] : 0;
        __syncthreads();
        sbuf[t] += x;
        __syncthreads();
    }
    const int n = cnts[b];
    const int base = sbuf[b] - n;       // exclusive prefix at bucket b
    const int2* sp = stage + (size_t)b * SCAP;
    for (int i = t; i < n; i += 256)
        atomicAdd(&cur[sp[i].x >> 17], 1);
    __syncthreads();
    int loc[5];
    int s = 0;
#pragma unroll
    for (int k = 0; k < 5; ++k) {
        int kk = t * 5 + k;
        int v = (kk < KPB) ? cur[kk] : 0;
        loc[k] = s;
        s += v;
    }
    tsum[t] = s;
    __syncthreads();
    for (int d = 1; d < 256; d <<= 1) {
        int x = (t >= d) ? tsum[t - d] : 0;
        __syncthreads();
        tsum[t] += x;
        __syncthreads();
    }
    int texcl = tsum[t] - s;
#pragma unroll
    for (int k = 0; k < 5; ++k) {
        int kk = t * 5 + k;
        if (kk < KPB) {
            int st0 = base + texcl + loc[k];
            int gk = b * KPB + kk;
            if (gk < CTOT) rstart[gk] = st0;
            cur[kk] = st0;
        }
    }
    __syncthreads();
    for (int i = t; i < n; i += 256) {
        int2 e = sp[i];
        int kl = e.x >> 17;
        int pos = atomicAdd(&cur[kl], 1);
        epair[pos] = make_int2(e.x & 0x1FFFF, e.y);
    }
}

struct GemmJob { const float* X; int xTile; int wIdx; int rowBase; int M; };
struct GemmTab { GemmJob j[3]; };

// round-4 gemm_glds body (scalar epilogue), parametrized block coords
__device__ __forceinline__ void gemm_core(const GemmJob& job,
                                          const __bf16* __restrict__ WtT,
                                          const __bf16* __restrict__ XbT,
                                          __bf16* __restrict__ T,
                                          char* smemraw, int bx, int by) {
    const int row0 = bx * 128;
    if (row0 >= job.M) return;
    const int M = job.M;
    __bf16* Als = (__bf16*)smemraw;         // 8 KB
    __bf16* Bls = Als + 4096;               // 8 KB
    const int t = threadIdx.x;
    const int col0 = by * 128;
    const int lane = t & 63, wave = t >> 6;
    const int q = lane >> 4, lm = lane & 15;
    const int wm = (wave & 1) * 64, wn = (wave >> 1) * 64;

    f32x4 acc[4][4];
    const f32x4 z = {0.f, 0.f, 0.f, 0.f};
#pragma unroll
    for (int i = 0; i < 4; ++i)
#pragma unroll
        for (int j = 0; j < 4; ++j) acc[i][j] = z;

    const int sb0 = wave * 128, sb1 = sb0 + 64;
    const int g0 = sb0 >> 7, m0 = (sb0 & 127) + lane;
    const int g1 = sb1 >> 7, m1 = (sb1 & 127) + lane;
    const __bf16* aSrc0 = XbT + (((size_t)(job.xTile + bx) * 32 + g0) * 128 + m0) * 8;
    const __bf16* aSrc1 = XbT + (((size_t)(job.xTile + bx) * 32 + g1) * 128 + m1) * 8;
    const __bf16* bSrc0 = WtT + (((size_t)(job.wIdx * 2 + by) * 32 + g0) * 128 + m0) * 8;
    const __bf16* bSrc1 = WtT + (((size_t)(job.wIdx * 2 + by) * 32 + g1) * 128 + m1) * 8;
    __bf16* aDst0 = &Als[(sb0 + lane) * 8];
    __bf16* aDst1 = &Als[(sb1 + lane) * 8];
    __bf16* bDst0 = &Bls[(sb0 + lane) * 8];
    __bf16* bDst1 = &Bls[(sb1 + lane) * 8];

    for (int it = 0; it < 8; ++it) {
        glds16(aSrc0, aDst0); glds16(aSrc1, aDst1);
        glds16(bSrc0, bDst0); glds16(bSrc1, bDst1);
        aSrc0 += 4096; aSrc1 += 4096; bSrc0 += 4096; bSrc1 += 4096;
        __syncthreads();
        bf16x8 af[4], bfr[4];
#pragma unroll
        for (int i = 0; i < 4; ++i)
            af[i] = *(bf16x8*)&Als[(q * 128 + wm + 16 * i + lm) * 8];
#pragma unroll
        for (int j = 0; j < 4; ++j)
            bfr[j] = *(bf16x8*)&Bls[(q * 128 + wn + 16 * j + lm) * 8];
#pragma unroll
        for (int i = 0; i < 4; ++i)
#pragma unroll
            for (int j = 0; j < 4; ++j)
                acc[i][j] = __builtin_amdgcn_mfma_f32_16x16x32_bf16(af[i], bfr[j], acc[i][j], 0, 0, 0);
        __syncthreads();
    }
#pragma unroll
    for (int i = 0; i < 4; ++i) {
        int gr0 = row0 + wm + 16 * i + q * 4;
#pragma unroll
        for (int r = 0; r < 4; ++r) {
            int grow = gr0 + r;
            if (grow < M) {
                __bf16* dst = T + (size_t)(job.rowBase + grow) * CC + col0 + wn + lm;
#pragma unroll
                for (int j = 0; j < 4; ++j) dst[16 * j] = (__bf16)acc[i][j][r];
            }
        }
    }
}

__device__ __forceinline__ void pool_core(const __bf16* __restrict__ acc,
                                          const int* __restrict__ seg,
                                          float* __restrict__ poolh, int n, int bid) {
    const unsigned short* A = (const unsigned short*)acc;
    int c = threadIdx.x;
    int node0 = bid * 64;
    int nend = min(node0 + 64, n);
    float run = 0.f;
    int curseg = seg[node0];
    for (int node = node0; node < nend; ++node) {
        int s = seg[node];
        float a = __uint_as_float((unsigned)A[(size_t)node * CC + c] << 16);
        float h = 1.f / (1.f + __expf(-a));
        if (s != curseg) {
            atomicAdd(&poolh[curseg * CC + c], run);
            run = 0.f; curseg = s;
        }
        run += h;
    }
    atomicAdd(&poolh[curseg * CC + c], run);
}

// ---- fused kernels --------------------------------------------------------

// launch 1: convert_x (XTTOT*4) | convert_w (224) | zero cursor/poolh/segc (1)
__global__ __launch_bounds__(256) void fused_prep(XcvtTab xt, WTab wt,
                                                  __bf16* __restrict__ XbT,
                                                  __bf16* __restrict__ WtT,
                                                  int* __restrict__ cursor,
                                                  float* __restrict__ poolh,
                                                  int* __restrict__ segc) {
    __shared__ __align__(16) char smemraw[16384];
    const int b = blockIdx.x;
    if (b < XTTOT * 4) {
        convert_x_core(xt, XbT, smemraw, b);
    } else if (b < XTTOT * 4 + 224) {
        convert_w_core(wt, WtT, b - XTTOT * 4);
    } else {
        const int t = threadIdx.x;
        cursor[t] = 0;
        for (int k = t; k < 3 * BB * CC; k += 256) poolh[k] = 0.f;
        if (t < 32) segc[t] = 0;
    }
}

// launch 2: bin_partition (nch) | seg_count (235)
__global__ __launch_bounds__(256) void part_seg(SrcTab st, int* __restrict__ cursor,
                                                int2* __restrict__ stage, int total, int nch,
                                                const int* s0, const int* s1, const int* s2,
                                                int* __restrict__ segc) {
    const int b = blockIdx.x;
    if (b < nch) partition_core(st, cursor, stage, total, b);
    else         seg_core(s0, s1, s2, segc, b - nch);
}

// launches 3/5/7: gemm jobs on z<njobs, extra work on z==njobs plane
__global__ __launch_bounds__(256) void gemm_scatter(GemmTab tab, int njobs,
                                                    const __bf16* __restrict__ WtT,
                                                    const __bf16* __restrict__ XbT,
                                                    __bf16* __restrict__ T,
                                                    const int2* __restrict__ stage,
                                                    const int* __restrict__ cnts,
                                                    int* __restrict__ rstart,
                                                    int2* __restrict__ epair) {
    __shared__ __align__(16) char smemraw[16384];
    if ((int)blockIdx.z < njobs) {
        gemm_core(tab.j[blockIdx.z], WtT, XbT, T, smemraw, blockIdx.x, blockIdx.y);
    } else {
        int flat = blockIdx.y * gridDim.x + blockIdx.x;
        if (flat < NBUK) scatter_core(stage, cnts, rstart, epair, smemraw, flat);
    }
}

__global__ __launch_bounds__(256) void gemm_pool(GemmTab tab, int njobs,
                                                 const __bf16* __restrict__ WtT,
                                                 const __bf16* __restrict__ XbT,
                                                 __bf16* __restrict__ T,
                                                 const __bf16* __restrict__ accb,
                                                 const int* __restrict__ seg,
                                                 float* __restrict__ poolh, int n) {
    __shared__ __align__(16) char smemraw[16384];
    if ((int)blockIdx.z < njobs) {
        gemm_core(tab.j[blockIdx.z], WtT, XbT, T, smemraw, blockIdx.x, blockIdx.y);
    } else {
        int flat = blockIdx.y * gridDim.x + blockIdx.x;
        if (flat < (n + 63) / 64) pool_core(accb, seg, poolh, n, flat);
    }
}

// ---- standalone kernels ---------------------------------------------------
__global__ __launch_bounds__(256) void pool_k(const __bf16* __restrict__ acc,
                                              const int* __restrict__ seg,
                                              float* __restrict__ poolh, int n) {
    pool_core(acc, seg, poolh, n, blockIdx.x);
}

__global__ __launch_bounds__(256) void bin_scatter_k(const int2* __restrict__ stage,
                                                     const int* __restrict__ cnts,
                                                     int* __restrict__ rstart,
                                                     int2* __restrict__ epair) {
    __shared__ __align__(16) char smemraw[16384];
    scatter_core(stage, cnts, rstart, epair, smemraw, blockIdx.x);
}

// old-path fallback pieces
__global__ void convert_w_old(WTab wt, __bf16* __restrict__ Wt) {
    int b = blockIdx.x;
    int w = b >> 8, n = b & 255;
    int k = threadIdx.x;
    Wt[((size_t)w * 256 + n) * 256 + k] = (__bf16)wt.w[w][k * 256 + n];
}

__global__ __launch_bounds__(256) void gemm_level(GemmTab tab,
                                                  const __bf16* __restrict__ WtAll,
                                                  __bf16* __restrict__ T) {
    const GemmJob job = tab.j[blockIdx.z];
    const int row0 = blockIdx.x * 128;
    if (row0 >= job.M) return;
    const int M = job.M;
    const float* __restrict__ X = job.X;
    const __bf16* __restrict__ Wt = WtAll + (size_t)job.wIdx * CC * CC;

    __shared__ __bf16 Als[4096];
    __shared__ __bf16 Bls[4096];
    const int t = threadIdx.x;
    const int col0 = blockIdx.y * 128;
    const int lane = t & 63, wave = t >> 6;
    const int q = lane >> 4, lm = lane & 15;
    const int wm = (wave & 1) * 64, wn = (wave >> 1) * 64;

    f32x4 acc[4][4];
    const f32x4 z = {0.f, 0.f, 0.f, 0.f};
#pragma unroll
    for (int i = 0; i < 4; ++i)
#pragma unroll
        for (int j = 0; j < 4; ++j) acc[i][j] = z;

    const int g0 = t >> 7, ms = t & 127;
    int arow = row0 + ms; if (arow > M - 1) arow = M - 1;
    const float*  ap = X  + (size_t)arow * CC;
    const __bf16* bp = Wt + (size_t)(col0 + ms) * CC;

    for (int kk = 0; kk < CC; kk += 32) {
#pragma unroll
        for (int s = 0; s < 2; ++s) {
            int g = g0 + s * 2;
            float4 f0 = *(const float4*)(ap + kk + g * 8);
            float4 f1 = *(const float4*)(ap + kk + g * 8 + 4);
            bf16x8 pk;
            pk[0] = (__bf16)f0.x; pk[1] = (__bf16)f0.y; pk[2] = (__bf16)f0.z; pk[3] = (__bf16)f0.w;
            pk[4] = (__bf16)f1.x; pk[5] = (__bf16)f1.y; pk[6] = (__bf16)f1.z; pk[7] = (__bf16)f1.w;
            *(bf16x8*)&Als[(g * 128 + ms) * 8] = pk;
            *(bf16x8*)&Bls[(g * 128 + ms) * 8] = *(const bf16x8*)(bp + kk + g * 8);
        }
        __syncthreads();
        bf16x8 af[4], bfr[4];
#pragma unroll
        for (int i = 0; i < 4; ++i)
            af[i] = *(bf16x8*)&Als[(q * 128 + wm + 16 * i + lm) * 8];
#pragma unroll
        for (int j = 0; j < 4; ++j)
            bfr[j] = *(bf16x8*)&Bls[(q * 128 + wn + 16 * j + lm) * 8];
#pragma unroll
        for (int i = 0; i < 4; ++i)
#pragma unroll
            for (int j = 0; j < 4; ++j)
                acc[i][j] = __builtin_amdgcn_mfma_f32_16x16x32_bf16(af[i], bfr[j], acc[i][j], 0, 0, 0);
        __syncthreads();
    }
#pragma unroll
    for (int i = 0; i < 4; ++i) {
        int gr0 = row0 + wm + 16 * i + q * 4;
#pragma unroll
        for (int r = 0; r < 4; ++r) {
            int grow = gr0 + r;
            if (grow < M) {
                __bf16* dst = T + (size_t)(job.rowBase + grow) * CC + col0 + wn + lm;
#pragma unroll
                for (int j = 0; j < 4; ++j) dst[16 * j] = (__bf16)acc[i][j][r];
            }
        }
    }
}

// ---------------------------------------------------------------------------
// fused per-level SPMM, gather pipelined x8/x4/x1
// ---------------------------------------------------------------------------
__global__ __launch_bounds__(256) void spmm_level(const int2* __restrict__ epair,
                                                  const int* __restrict__ rstart,
                                                  const __bf16* __restrict__ T,
                                                  __bf16* __restrict__ acc,
                                                  int Kb, int S, int nrows) {
    int row = blockIdx.x * 4 + (threadIdx.x >> 6);
    if (row >= nrows) return;
    int l = threadIdx.x & 63;
    int s0 = rstart[Kb + row * S];
    int e = rstart[Kb + row * S + S];
    const unsigned short* Tb = (const unsigned short*)T + l * 4;
    float4 a0 = make_float4(0.f, 0.f, 0.f, 0.f);
    for (int base = s0; base < e; base += 64) {
        int j = base + l;
        int off = 0; float v = 0.f;
        if (j < e) { int2 ee = epair[j]; off = ee.x; v = __int_as_float(ee.y); }
        int lim = e - base; if (lim > 64) lim = 64;
        int i = 0;
        for (; i + 8 <= lim; i += 8) {
            int ob[8]; float vb[8]; uint2 u[8];
#pragma unroll
            for (int p = 0; p < 8; ++p) { ob[p] = __shfl(off, i + p, 64); vb[p] = __shfl(v, i + p, 64); }
#pragma unroll
            for (int p = 0; p < 8; ++p) u[p] = *(const uint2*)(Tb + (size_t)ob[p] * CC);
#pragma unroll
            for (int p = 0; p < 8; ++p) {
                a0.x += vb[p] * __uint_as_float(u[p].x << 16);
                a0.y += vb[p] * __uint_as_float(u[p].x & 0xFFFF0000u);
                a0.z += vb[p] * __uint_as_float(u[p].y << 16);
                a0.w += vb[p] * __uint_as_float(u[p].y & 0xFFFF0000u);
            }
        }
        for (; i + 4 <= lim; i += 4) {
            int ob[4]; float vb[4]; uint2 u[4];
#pragma unroll
            for (int p = 0; p < 4; ++p) { ob[p] = __shfl(off, i + p, 64); vb[p] = __shfl(v, i + p, 64); }
#pragma unroll
            for (int p = 0; p < 4; ++p) u[p] = *(const uint2*)(Tb + (size_t)ob[p] * CC);
#pragma unroll
            for (int p = 0; p < 4; ++p) {
                a0.x += vb[p] * __uint_as_float(u[p].x << 16);
                a0.y += vb[p] * __uint_as_float(u[p].x & 0xFFFF0000u);
                a0.z += vb[p] * __uint_as_float(u[p].y << 16);
                a0.w += vb[p] * __uint_as_float(u[p].y & 0xFFFF0000u);
            }
        }
        for (; i < lim; ++i) {
            int   ob = __shfl(off, i, 64);
            float vb = __shfl(v, i, 64);
            uint2 u = *(const uint2*)(Tb + (size_t)ob * CC);
            a0.x += vb * __uint_as_float(u.x << 16);
            a0.y += vb * __uint_as_float(u.x & 0xFFFF0000u);
            a0.z += vb * __uint_as_float(u.y << 16);
            a0.w += vb * __uint_as_float(u.y & 0xFFFF0000u);
        }
    }
    bf16x4 o;
    o[0] = (__bf16)a0.x; o[1] = (__bf16)a0.y; o[2] = (__bf16)a0.z; o[3] = (__bf16)a0.w;
    *(bf16x4*)(acc + (size_t)row * CC + l * 4) = o;
}

__global__ __launch_bounds__(64) void final_head(const float* __restrict__ ph0,
                                                 const float* __restrict__ ph1,
                                                 const float* __restrict__ ph2,
                                                 const int* __restrict__ c0,
                                                 const int* __restrict__ c1,
                                                 const int* __restrict__ c2,
                                                 const float* __restrict__ W0,
                                                 const float* __restrict__ W1,
                                                 const float* __restrict__ W2,
                                                 const float* __restrict__ b0,
                                                 const float* __restrict__ b1,
                                                 const float* __restrict__ b2,
                                                 float* __restrict__ out) {
    int s = blockIdx.x, o = threadIdx.x;
    float inv0 = 1.f / fmaxf((float)c0[s], 1.f);
    float inv1 = 1.f / fmaxf((float)c1[s], 1.f);
    float inv2 = 1.f / fmaxf((float)c2[s], 1.f);
    float a0 = 0.f, a1 = 0.f, a2 = 0.f;
    for (int k = 0; k < CC; ++k) {
        a0 += ph0[s * CC + k] * W0[k * OUTD + o];
        a1 += ph1[s * CC + k] * W1[k * OUTD + o];
        a2 += ph2[s * CC + k] * W2[k * OUTD + o];
    }
    out[s * OUTD + o] = (a0 * inv0 + b0[o] + a1 * inv1 + b1[o] + a2 * inv2 + b2[o]) * (1.f / 3.f);
}

// ---------------------------------------------------------------------------
extern "C" void kernel_launch(void* const* d_in, const int* in_sizes, int n_in,
                              void* d_out, int out_size, void* d_ws, size_t ws_size,
                              hipStream_t stream) {
    const float* x0 = (const float*)d_in[0];
    const float* x1 = (const float*)d_in[1];
    const float* x2 = (const float*)d_in[2];
    const int* belong0 = (const int*)d_in[27];
    const int* belong1 = (const int*)d_in[28];
    const int* belong2 = (const int*)d_in[29];

    // ---- workspace layout (bytes) ----
    char* w = (char*)d_ws;
    __bf16* T    = (__bf16*)w;  w += (size_t)120000 * CC * 2;  // 61.44 MB
    __bf16* accb = (__bf16*)w;  w += (size_t)NN1 * CC * 2;     // 30.72 MB (stage aliases this)
    __bf16* Wt   = (__bf16*)w;  w += (size_t)7 * CC * CC * 2;
    int2*   epair= (int2*)w;    w += (size_t)ECAP * 8;
    int*  bucketCursor = (int*)w; w += NBUK * 4;
    float*  poolh= (float*)w;   w += 3 * BB * CC * 4;
    int*    segc = (int*)w;     w += 32 * 4;
    int*    rstart=(int*)w;     w += (size_t)CTOT * 4;
    __bf16* XbT  = (__bf16*)w;  w += (size_t)XTTOT * 4096 * 16; // 61.54 MB
    size_t required_new = (size_t)(w - (char*)d_ws);
    int* cnt0 = segc, *cnt1 = segc + 8, *cnt2 = segc + 16;
    const bool use_glds = (ws_size >= required_new);

    // radix staging aliases accb: written by part_seg (launch 2), read by the
    // scatter plane of launch 3; accb is first written by spmm L0 (launch 4).
    int2* stage = (int2*)accb;   // NBUK*SCAP*8 = 25.2 MB <= 30.72 MB

    // ---- source table: order adj0, inc1 | inc1t, adjd1, adju1, inc2 | inc2t, adjd2
    const int bases[8] = {15, 3, 9, 21, 18, 6, 12, 24};
    const int kbase[8] = {KB_L0, KB_L0, KB_L1, KB_L1, KB_L1, KB_L1, KB_L2, KB_L2};
    const int mulS [8] = {2, 2, 3, 3, 3, 3, 2, 2};
    const int slot [8] = {0, 1, 0, 1, 1, 2, 0, 1};
    const int tbase[8] = {0, 20000, 0, 20000, 20000, 80000, 0, 60000};
    SrcTab st;
    int run = 0;
    for (int s = 0; s < 8; ++s) {
        st.rows[s] = (const int*)d_in[bases[s]];
        st.cols[s] = (const int*)d_in[bases[s] + 1];
        st.vals[s] = (const float*)d_in[bases[s] + 2];
        st.kbase[s] = kbase[s]; st.mulS[s] = mulS[s];
        st.slot[s] = slot[s];   st.tbase[s] = tbase[s];
        st.pre[s] = run;
        run += in_sizes[bases[s]];
    }
    st.pre[8] = run;
    const int total = run;
    const int nch = (total + ACHUNK - 1) / ACHUNK;
    const int nsegb = (NN1 + 255) / 256;

    WTab wt;
    for (int i = 0; i < 7; ++i) wt.w[i] = (const float*)d_in[30 + i];

    if (use_glds) {
        XcvtTab xt;
        xt.src[0] = x0; xt.src[1] = x1; xt.src[2] = x2;
        xt.tstart[0] = XT0; xt.tstart[1] = XT1; xt.tstart[2] = XT2; xt.tstart[3] = XTTOT;
        xt.nrows[0] = NN0; xt.nrows[1] = NN1; xt.nrows[2] = NN2;

        // 1: convert_x | convert_w | zero(cursor, poolh, segc)
        fused_prep<<<XTTOT * 4 + 224 + 1, 256, 0, stream>>>(xt, wt, XbT, Wt,
                                                            bucketCursor, poolh, segc);
        // 2: bin_partition | seg_count
        part_seg<<<nch + nsegb, 256, 0, stream>>>(st, bucketCursor, stage, total, nch,
                                                  belong0, belong1, belong2, segc);
        // 3: gemm L0 (z<2) | bin_scatter+scan (z==2)
        {
            GemmTab g;
            g.j[0] = {x0, XT0, 0, 0, NN0};
            g.j[1] = {x1, XT1, 1, 20000, NN1};
            gemm_scatter<<<dim3(GXB, 2, 3), 256, 0, stream>>>(g, 2, Wt, XbT, T,
                                                              stage, bucketCursor, rstart, epair);
        }
        // 4: spmm L0
        spmm_level<<<(NN0 + 3) / 4, 256, 0, stream>>>(epair, rstart, T, accb, KB_L0, 2, NN0);
        // 5: gemm L1 (z<3) | pool L0 (z==3)
        {
            GemmTab g;
            g.j[0] = {x0, XT0, 2, 0, NN0};
            g.j[1] = {x1, XT1, 3, 20000, NN1};
            g.j[2] = {x2, XT2, 4, 80000, NN2};
            gemm_pool<<<dim3(GXB, 2, 4), 256, 0, stream>>>(g, 3, Wt, XbT, T,
                                                           accb, belong0, poolh, NN0);
        }
        // 6: spmm L1
        spmm_level<<<(NN1 + 3) / 4, 256, 0, stream>>>(epair, rstart, T, accb, KB_L1, 3, NN1);
        // 7: gemm L2 (z<2) | pool L1 (z==2)
        {
            GemmTab g;
            g.j[0] = {x1, XT1, 5, 0, NN1};
            g.j[1] = {x2, XT2, 6, 60000, NN2};
            gemm_pool<<<dim3(GXB, 2, 3), 256, 0, stream>>>(g, 2, Wt, XbT, T,
                                                           accb, belong1, poolh + BB * CC, NN1);
        }
        // 8: spmm L2
        spmm_level<<<(NN2 + 3) / 4, 256, 0, stream>>>(epair, rstart, T, accb, KB_L2, 2, NN2);
        // 9: pool L2
        pool_k<<<(NN2 + 63) / 64, 256, 0, stream>>>(accb, belong2, poolh + 2 * BB * CC, NN2);
        // 10: final
        final_head<<<BB, 64, 0, stream>>>(poolh, poolh + BB * CC, poolh + 2 * BB * CC,
                                          cnt0, cnt1, cnt2,
                                          (const float*)d_in[37], (const float*)d_in[38],
                                          (const float*)d_in[39], (const float*)d_in[40],
                                          (const float*)d_in[41], (const float*)d_in[42],
                                          (float*)d_out);
    } else {
        // fallback: separate launches, fp32-X GEMM
        zero_kernel<<<8, 256, 0, stream>>>((float4*)bucketCursor,
                                           (NBUK * 4 + 3 * BB * CC * 4 + 128) / 16);
        part_seg<<<nch + nsegb, 256, 0, stream>>>(st, bucketCursor, stage, total, nch,
                                                  belong0, belong1, belong2, segc);
        convert_w_old<<<7 * 256, 256, 0, stream>>>(wt, Wt);
        bin_scatter_k<<<NBUK, 256, 0, stream>>>(stage, bucketCursor, rstart, epair);
        {
            GemmTab g;
            g.j[0] = {x0, XT0, 0, 0, NN0};
            g.j[1] = {x1, XT1, 1, 20000, NN1};
            gemm_level<<<dim3(GXB, 2, 2), 256, 0, stream>>>(g, Wt, T);
            spmm_level<<<(NN0 + 3) / 4, 256, 0, stream>>>(epair, rstart, T, accb, KB_L0, 2, NN0);
            pool_k<<<(NN0 + 63) / 64, 256, 0, stream>>>(accb, belong0, poolh, NN0);
        }
        {
            GemmTab g;
            g.j[0] = {x0, XT0, 2, 0, NN0};
            g.j[1] = {x1, XT1, 3, 20000, NN1};
            g.j[2] = {x2, XT2, 4, 80000, NN2};
            gemm_level<<<dim3(GXB, 2, 3), 256, 0, stream>>>(g, Wt, T);
            spmm_level<<<(NN1 + 3) / 4, 256, 0, stream>>>(epair, rstart, T, accb, KB_L1, 3, NN1);
            pool_k<<<(NN1 + 63) / 64, 256, 0, stream>>>(accb, belong1, poolh + BB * CC, NN1);
        }
        {
            GemmTab g;
            g.j[0] = {x1, XT1, 5, 0, NN1};
            g.j[1] = {x2, XT2, 6, 60000, NN2};
            gemm_level<<<dim3(GXB, 2, 2), 256, 0, stream>>>(g, Wt, T);
            spmm_level<<<(NN2 + 3) / 4, 256, 0, stream>>>(epair, rstart, T, accb, KB_L2, 2, NN2);
            pool_k<<<(NN2 + 63) / 64, 256, 0, stream>>>(accb, belong2, poolh + 2 * BB * CC, NN2);
        }
        final_head<<<BB, 64, 0, stream>>>(poolh, poolh + BB * CC, poolh + 2 * BB * CC,
                                          cnt0, cnt1, cnt2,
                                          (const float*)d_in[37], (const float*)d_in[38],
                                          (const float*)d_in[39], (const float*)d_in[40],
                                          (const float*)d_in[41], (const float*)d_in[42],
                                          (float*)d_out);
    }
}

// Round 9
// 526.023 us; speedup vs baseline: 1.1396x; 1.0650x over previous
//
#include <hip/hip_runtime.h>
#include <math.h>

#define NN0 20000
#define NN1 60000
#define NN2 40000
#define CC 256
#define OUTD 64
#define BB 8

// key space: L0 = row*2+slot in [0,40000); L1 = 40000+row*3+slot; L2 = 220000+row*2+slot
#define KB_L0 0
#define KB_L1 40000
#define KB_L2 220000
#define CTOT  300288
#define ECAP  1300000

// radix partition params
#define NBUK  256
#define KPB   1174
#define SCAP  12288
#define ACHUNK 4096

// X tiling (128-row tiles): x0 157, x1 469, x2 313 -> 939 tiles
#define XT0 0
#define XT1 157
#define XT2 626
#define XTTOT 939
#define GXB 469           // (NN1+127)/128
#define X4  (XTTOT * 4)   // 3756 convert_x blocks
#define WB  224           // convert_w blocks

typedef __bf16 bf16x8 __attribute__((ext_vector_type(8)));
typedef __bf16 bf16x4 __attribute__((ext_vector_type(4)));
typedef float  f32x4  __attribute__((ext_vector_type(4)));

__device__ __forceinline__ void glds16(const __bf16* g, __bf16* l) {
    __builtin_amdgcn_global_load_lds(
        (const __attribute__((address_space(1))) void*)g,
        (__attribute__((address_space(3))) void*)l, 16, 0, 0);
}

// ---------------------------------------------------------------------------
__global__ void zero_kernel(float4* __restrict__ p, long n4) {
    long i = (long)blockIdx.x * blockDim.x + threadIdx.x;
    long stride = (long)gridDim.x * blockDim.x;
    for (; i < n4; i += stride) p[i] = make_float4(0.f, 0.f, 0.f, 0.f);
}

// ---------------------------------------------------------------------------
struct WTab { const float* w[7]; };
struct XcvtTab { const float* src[3]; int tstart[4]; int nrows[3]; };

// ---- device cores ---------------------------------------------------------

__device__ __forceinline__ void convert_x_core(const XcvtTab& xt, __bf16* __restrict__ XbT,
                                               char* smemraw, int b) {
    __bf16* ls = (__bf16*)smemraw;   // 16 KB
    const int tile = b >> 2, cb = b & 3;
    int s = (tile >= xt.tstart[1] ? 1 : 0) + (tile >= xt.tstart[2] ? 1 : 0);
    const float* src = xt.src[s];
    const int row0 = (tile - xt.tstart[s]) * 128;
    const int nrows = xt.nrows[s];
    __bf16* dst = XbT + ((size_t)tile * 4096 + (size_t)cb * 1024) * 8;
    const int t = threadIdx.x;
    const int rr = t >> 4;
    const int c4 = (t & 15) * 4;
    const int gl = c4 >> 3;
    const int sub = c4 & 7;
    const int xorbits = (gl & 7) << 4;
#pragma unroll
    for (int jj = 0; jj < 8; ++jj) {
        int r = jj * 16 + rr;
        int gr = row0 + r;
        float4 f;
        if (gr < nrows) f = *(const float4*)(src + (size_t)gr * CC + cb * 64 + c4);
        else            f = make_float4(0.f, 0.f, 0.f, 0.f);
        bf16x4 pk;
        pk[0] = (__bf16)f.x; pk[1] = (__bf16)f.y; pk[2] = (__bf16)f.z; pk[3] = (__bf16)f.w;
        int byteoff = (gl * 2048 + r * 16 + sub * 2) ^ xorbits;
        *(bf16x4*)((char*)ls + byteoff) = pk;
    }
    __syncthreads();
#pragma unroll
    for (int j = 0; j < 4; ++j) {
        int sidx = j * 256 + t;
        int byteoff = (sidx * 16) ^ (((sidx >> 7) & 7) << 4);
        *(bf16x8*)(dst + (size_t)sidx * 8) = *(bf16x8*)((char*)ls + byteoff);
    }
}

__device__ __forceinline__ void convert_w_core(const WTab& wt, __bf16* __restrict__ WtT, int wb) {
    int idx = wb * 256 + threadIdx.x;
    int w = idx >> 13;
    int rem = idx & 8191;
    int cb = rem >> 12;
    int rem2 = rem & 4095;
    int g = rem2 >> 7, n = rem2 & 127;
    const float* W = wt.w[w];
    int col = cb * 128 + n;
    bf16x8 pk;
#pragma unroll
    for (int j = 0; j < 8; ++j) pk[j] = (__bf16)W[(g * 8 + j) * CC + col];
    *(bf16x8*)(WtT + (size_t)idx * 8) = pk;
}

__device__ __forceinline__ void seg_core(const int* s0, const int* s1, const int* s2,
                                         int* cnt, int blk) {
    int i = blk * 256 + threadIdx.x;
    int a = (i < NN0) ? s0[i] : -1;
    int b = (i < NN1) ? s1[i] : -1;
    int c = (i < NN2) ? s2[i] : -1;
#pragma unroll
    for (int v = 0; v < BB; ++v) {
        unsigned long long m0 = __ballot(a == v);
        unsigned long long m1 = __ballot(b == v);
        unsigned long long m2 = __ballot(c == v);
        if ((threadIdx.x & 63) == 0) {
            if (m0) atomicAdd(&cnt[v], (int)__popcll(m0));
            if (m1) atomicAdd(&cnt[8 + v], (int)__popcll(m1));
            if (m2) atomicAdd(&cnt[16 + v], (int)__popcll(m2));
        }
    }
}

struct SrcTab {
    const int*   rows[8];
    const int*   cols[8];
    const float* vals[8];
    int pre[9];
    int kbase[8];
    int mulS[8];
    int slot[8];
    int tbase[8];
};

__device__ __forceinline__ void partition_core(const SrcTab& st, int* __restrict__ bucketCursor,
                                               int2* __restrict__ stage, int total, int chunk) {
    __shared__ int hist[NBUK];
    __shared__ int bbase[NBUK];
    const int t = threadIdx.x;
    hist[t] = 0;
    __syncthreads();
    const int base0 = chunk * ACHUNK;
    int2 ent[16];
    int  meta[16];
#pragma unroll
    for (int k = 0; k < 16; ++k) {
        int i = base0 + k * 256 + t;
        if (i < total) {
            int s = 0;
            while (i >= st.pre[s + 1]) ++s;
            int j = i - st.pre[s];
            int key = st.kbase[s] + st.rows[s][j] * st.mulS[s] + st.slot[s];
            int bkt = key / KPB;
            int kl = key - bkt * KPB;
            ent[k] = make_int2((kl << 17) | (st.cols[s][j] + st.tbase[s]),
                               __float_as_int(st.vals[s][j]));
            int r = atomicAdd(&hist[bkt], 1);
            meta[k] = (bkt << 16) | r;
        } else {
            meta[k] = -1;
        }
    }
    __syncthreads();
    bbase[t] = atomicAdd(&bucketCursor[t], hist[t]);
    __syncthreads();
#pragma unroll
    for (int k = 0; k < 16; ++k) {
        if (meta[k] >= 0) {
            int bkt = meta[k] >> 16, r = meta[k] & 0xFFFF;
            stage[(size_t)bkt * SCAP + bbase[bkt] + r] = ent[k];
        }
    }
}

__device__ __forceinline__ void scatter_core(const int2* __restrict__ stage,
                                             const int* __restrict__ cnts,
                                             int* __restrict__ rstart,
                                             int2* __restrict__ epair,
                                             char* smemraw, int b) {
    int* cur  = (int*)smemraw;          // KPB
    int* tsum = cur + KPB;              // 256
    int* sbuf = tsum + 256;             // 256
    const int t = threadIdx.x;
    for (int k = t; k < KPB; k += 256) cur[k] = 0;
    sbuf[t] = cnts[t];
    __syncthreads();
    for (int d = 1; d < 256; d <<= 1) {
        int x = (t >= d) ? sbuf[t - d] : 0;
        __syncthreads();
        sbuf[t] += x;
        __syncthreads();
    }
    const int n = cnts[b];
    const int base = sbuf[b] - n;
    const int2* sp = stage + (size_t)b * SCAP;
    for (int i = t; i < n; i += 256)
        atomicAdd(&cur[sp[i].x >> 17], 1);
    __syncthreads();
    int loc[5];
    int s = 0;
#pragma unroll
    for (int k = 0; k < 5; ++k) {
        int kk = t * 5 + k;
        int v = (kk < KPB) ? cur[kk] : 0;
        loc[k] = s;
        s += v;
    }
    tsum[t] = s;
    __syncthreads();
    for (int d = 1; d < 256; d <<= 1) {
        int x = (t >= d) ? tsum[t - d] : 0;
        __syncthreads();
        tsum[t] += x;
        __syncthreads();
    }
    int texcl = tsum[t] - s;
#pragma unroll
    for (int k = 0; k < 5; ++k) {
        int kk = t * 5 + k;
        if (kk < KPB) {
            int st0 = base + texcl + loc[k];
            int gk = b * KPB + kk;
            if (gk < CTOT) rstart[gk] = st0;
            cur[kk] = st0;
        }
    }
    __syncthreads();
    for (int i = t; i < n; i += 256) {
        int2 e = sp[i];
        int kl = e.x >> 17;
        int pos = atomicAdd(&cur[kl], 1);
        epair[pos] = make_int2(e.x & 0x1FFFF, e.y);
    }
}

struct GemmJob { const float* X; int xTile; int wIdx; int rowBase; int M; };
struct GemmTab { GemmJob j[3]; };

__device__ __forceinline__ void gemm_core(const GemmJob& job,
                                          const __bf16* __restrict__ WtT,
                                          const __bf16* __restrict__ XbT,
                                          __bf16* __restrict__ T,
                                          char* smemraw, int bx, int by) {
    const int row0 = bx * 128;
    if (row0 >= job.M) return;      // block-uniform
    const int M = job.M;
    __bf16* Als = (__bf16*)smemraw;
    __bf16* Bls = Als + 4096;
    const int t = threadIdx.x;
    const int col0 = by * 128;
    const int lane = t & 63, wave = t >> 6;
    const int q = lane >> 4, lm = lane & 15;
    const int wm = (wave & 1) * 64, wn = (wave >> 1) * 64;

    f32x4 acc[4][4];
    const f32x4 z = {0.f, 0.f, 0.f, 0.f};
#pragma unroll
    for (int i = 0; i < 4; ++i)
#pragma unroll
        for (int j = 0; j < 4; ++j) acc[i][j] = z;

    const int sb0 = wave * 128, sb1 = sb0 + 64;
    const int g0 = sb0 >> 7, m0 = (sb0 & 127) + lane;
    const int g1 = sb1 >> 7, m1 = (sb1 & 127) + lane;
    const __bf16* aSrc0 = XbT + (((size_t)(job.xTile + bx) * 32 + g0) * 128 + m0) * 8;
    const __bf16* aSrc1 = XbT + (((size_t)(job.xTile + bx) * 32 + g1) * 128 + m1) * 8;
    const __bf16* bSrc0 = WtT + (((size_t)(job.wIdx * 2 + by) * 32 + g0) * 128 + m0) * 8;
    const __bf16* bSrc1 = WtT + (((size_t)(job.wIdx * 2 + by) * 32 + g1) * 128 + m1) * 8;
    __bf16* aDst0 = &Als[(sb0 + lane) * 8];
    __bf16* aDst1 = &Als[(sb1 + lane) * 8];
    __bf16* bDst0 = &Bls[(sb0 + lane) * 8];
    __bf16* bDst1 = &Bls[(sb1 + lane) * 8];

    for (int it = 0; it < 8; ++it) {
        glds16(aSrc0, aDst0); glds16(aSrc1, aDst1);
        glds16(bSrc0, bDst0); glds16(bSrc1, bDst1);
        aSrc0 += 4096; aSrc1 += 4096; bSrc0 += 4096; bSrc1 += 4096;
        __syncthreads();
        bf16x8 af[4], bfr[4];
#pragma unroll
        for (int i = 0; i < 4; ++i)
            af[i] = *(bf16x8*)&Als[(q * 128 + wm + 16 * i + lm) * 8];
#pragma unroll
        for (int j = 0; j < 4; ++j)
            bfr[j] = *(bf16x8*)&Bls[(q * 128 + wn + 16 * j + lm) * 8];
#pragma unroll
        for (int i = 0; i < 4; ++i)
#pragma unroll
            for (int j = 0; j < 4; ++j)
                acc[i][j] = __builtin_amdgcn_mfma_f32_16x16x32_bf16(af[i], bfr[j], acc[i][j], 0, 0, 0);
        __syncthreads();
    }
#pragma unroll
    for (int i = 0; i < 4; ++i) {
        int gr0 = row0 + wm + 16 * i + q * 4;
#pragma unroll
        for (int r = 0; r < 4; ++r) {
            int grow = gr0 + r;
            if (grow < M) {
                __bf16* dst = T + (size_t)(job.rowBase + grow) * CC + col0 + wn + lm;
#pragma unroll
                for (int j = 0; j < 4; ++j) dst[16 * j] = (__bf16)acc[i][j][r];
            }
        }
    }
}

__device__ __forceinline__ void pool_core(const __bf16* __restrict__ acc,
                                          const int* __restrict__ seg,
                                          float* __restrict__ poolh, int n, int bid) {
    const unsigned short* A = (const unsigned short*)acc;
    int c = threadIdx.x;
    int node0 = bid * 64;
    int nend = min(node0 + 64, n);
    float run = 0.f;
    int curseg = seg[node0];
    for (int node = node0; node < nend; ++node) {
        int s = seg[node];
        float a = __uint_as_float((unsigned)A[(size_t)node * CC + c] << 16);
        float h = 1.f / (1.f + __expf(-a));
        if (s != curseg) {
            atomicAdd(&poolh[curseg * CC + c], run);
            run = 0.f; curseg = s;
        }
        run += h;
    }
    atomicAdd(&poolh[curseg * CC + c], run);
}

// spmm for one 4-row group (no barriers; safe to early-return per-wave)
__device__ __forceinline__ void spmm_group(const int2* __restrict__ epair,
                                           const int* __restrict__ rstart,
                                           const __bf16* __restrict__ T,
                                           __bf16* __restrict__ acc,
                                           int Kb, int S, int nrows, int grp) {
    int row = grp * 4 + (threadIdx.x >> 6);
    if (row >= nrows) return;
    int l = threadIdx.x & 63;
    int s0 = rstart[Kb + row * S];
    int e = rstart[Kb + row * S + S];
    const unsigned short* Tb = (const unsigned short*)T + l * 4;
    float4 a0 = make_float4(0.f, 0.f, 0.f, 0.f);
    for (int base = s0; base < e; base += 64) {
        int j = base + l;
        int off = 0; float v = 0.f;
        if (j < e) { int2 ee = epair[j]; off = ee.x; v = __int_as_float(ee.y); }
        int lim = e - base; if (lim > 64) lim = 64;
        int i = 0;
        for (; i + 8 <= lim; i += 8) {
            int ob[8]; float vb[8]; uint2 u[8];
#pragma unroll
            for (int p = 0; p < 8; ++p) { ob[p] = __shfl(off, i + p, 64); vb[p] = __shfl(v, i + p, 64); }
#pragma unroll
            for (int p = 0; p < 8; ++p) u[p] = *(const uint2*)(Tb + (size_t)ob[p] * CC);
#pragma unroll
            for (int p = 0; p < 8; ++p) {
                a0.x += vb[p] * __uint_as_float(u[p].x << 16);
                a0.y += vb[p] * __uint_as_float(u[p].x & 0xFFFF0000u);
                a0.z += vb[p] * __uint_as_float(u[p].y << 16);
                a0.w += vb[p] * __uint_as_float(u[p].y & 0xFFFF0000u);
            }
        }
        for (; i + 4 <= lim; i += 4) {
            int ob[4]; float vb[4]; uint2 u[4];
#pragma unroll
            for (int p = 0; p < 4; ++p) { ob[p] = __shfl(off, i + p, 64); vb[p] = __shfl(v, i + p, 64); }
#pragma unroll
            for (int p = 0; p < 4; ++p) u[p] = *(const uint2*)(Tb + (size_t)ob[p] * CC);
#pragma unroll
            for (int p = 0; p < 4; ++p) {
                a0.x += vb[p] * __uint_as_float(u[p].x << 16);
                a0.y += vb[p] * __uint_as_float(u[p].x & 0xFFFF0000u);
                a0.z += vb[p] * __uint_as_float(u[p].y << 16);
                a0.w += vb[p] * __uint_as_float(u[p].y & 0xFFFF0000u);
            }
        }
        for (; i < lim; ++i) {
            int   ob = __shfl(off, i, 64);
            float vb = __shfl(v, i, 64);
            uint2 u = *(const uint2*)(Tb + (size_t)ob * CC);
            a0.x += vb * __uint_as_float(u.x << 16);
            a0.y += vb * __uint_as_float(u.x & 0xFFFF0000u);
            a0.z += vb * __uint_as_float(u.y << 16);
            a0.w += vb * __uint_as_float(u.y & 0xFFFF0000u);
        }
    }
    bf16x4 o;
    o[0] = (__bf16)a0.x; o[1] = (__bf16)a0.y; o[2] = (__bf16)a0.z; o[3] = (__bf16)a0.w;
    *(bf16x4*)(acc + (size_t)row * CC + l * 4) = o;
}

// ---- overlap-path fused kernels -------------------------------------------

// launch 1: partition (nch) | seg (nsegb) | convert_w (224) | convert_x (3756)
__global__ __launch_bounds__(256) void mega_prep(XcvtTab xt, WTab wt, SrcTab st,
                                                 __bf16* __restrict__ XbT,
                                                 __bf16* __restrict__ WtT,
                                                 int* __restrict__ cursor,
                                                 int2* __restrict__ stage, int total, int nch,
                                                 const int* s0, const int* s1, const int* s2,
                                                 int* __restrict__ segc, int nsegb) {
    __shared__ __align__(16) char smemraw[16384];
    const int b = blockIdx.x;
    if (b < nch)                      partition_core(st, cursor, stage, total, b);
    else if (b < nch + nsegb)         seg_core(s0, s1, s2, segc, b - nch);
    else if (b < nch + nsegb + WB)    convert_w_core(wt, WtT, b - nch - nsegb);
    else                              convert_x_core(xt, XbT, smemraw, b - nch - nsegb - WB);
}

// launch 2: gemm L0 (z<2, ->Ta) | scatter (z==2)
__global__ __launch_bounds__(256) void gemm_scatter(GemmTab tab, int njobs,
                                                    const __bf16* __restrict__ WtT,
                                                    const __bf16* __restrict__ XbT,
                                                    __bf16* __restrict__ T,
                                                    const int2* __restrict__ stage,
                                                    const int* __restrict__ cnts,
                                                    int* __restrict__ rstart,
                                                    int2* __restrict__ epair) {
    __shared__ __align__(16) char smemraw[16384];
    if ((int)blockIdx.z < njobs) {
        gemm_core(tab.j[blockIdx.z], WtT, XbT, T, smemraw, blockIdx.x, blockIdx.y);
    } else {
        int flat = blockIdx.y * gridDim.x + blockIdx.x;
        if (flat < NBUK) scatter_core(stage, cnts, rstart, epair, smemraw, flat);
    }
}

// launch 3: gemm L1 (3 jobs ->Tb, blocks [0,2814)) | spmm L0 (Ta->accA)
__global__ __launch_bounds__(256) void gemm1_spmm0(GemmTab g,
                                                   const __bf16* __restrict__ WtT,
                                                   const __bf16* __restrict__ XbT,
                                                   __bf16* __restrict__ Tb,
                                                   const int2* __restrict__ epair,
                                                   const int* __restrict__ rstart,
                                                   const __bf16* __restrict__ Ta,
                                                   __bf16* __restrict__ accA) {
    __shared__ __align__(16) char smemraw[16384];
    const int b = blockIdx.x;
    if (b < 3 * 2 * GXB) {
        int z = b / (2 * GXB), rem = b % (2 * GXB);
        gemm_core(g.j[z], WtT, XbT, Tb, smemraw, rem % GXB, rem / GXB);
    } else {
        spmm_group(epair, rstart, Ta, accA, KB_L0, 2, NN0, b - 3 * 2 * GXB);
    }
}

// launch 4: gemm L2 (2 jobs ->Ta, [0,1876)) | pool L0 (accA) | spmm L1 (Tb->accB)
__global__ __launch_bounds__(256) void gemm2_pool0_spmm1(GemmTab g,
                                                         const __bf16* __restrict__ WtT,
                                                         const __bf16* __restrict__ XbT,
                                                         __bf16* __restrict__ Ta,
                                                         const __bf16* __restrict__ accA,
                                                         const int* __restrict__ seg0,
                                                         float* __restrict__ ph0,
                                                         const int2* __restrict__ epair,
                                                         const int* __restrict__ rstart,
                                                         const __bf16* __restrict__ Tb,
                                                         __bf16* __restrict__ accB) {
    __shared__ __align__(16) char smemraw[16384];
    const int b = blockIdx.x;
    const int NG = 2 * 2 * GXB;          // 1876
    const int NP = (NN0 + 63) / 64;      // 313
    if (b < NG) {
        int z = b / (2 * GXB), rem = b % (2 * GXB);
        gemm_core(g.j[z], WtT, XbT, Ta, smemraw, rem % GXB, rem / GXB);
    } else if (b < NG + NP) {
        pool_core(accA, seg0, ph0, NN0, b - NG);
    } else {
        spmm_group(epair, rstart, Tb, accB, KB_L1, 3, NN1, b - NG - NP);
    }
}

// launch 5: pool L1 (accB) | spmm L2 (Ta->accA)
__global__ __launch_bounds__(256) void pool1_spmm2(const __bf16* __restrict__ accB,
                                                   const int* __restrict__ seg1,
                                                   float* __restrict__ ph1,
                                                   const int2* __restrict__ epair,
                                                   const int* __restrict__ rstart,
                                                   const __bf16* __restrict__ Ta,
                                                   __bf16* __restrict__ accA) {
    const int b = blockIdx.x;
    const int NP = (NN1 + 63) / 64;      // 938
    if (b < NP) pool_core(accB, seg1, ph1, NN1, b);
    else        spmm_group(epair, rstart, Ta, accA, KB_L2, 2, NN2, b - NP);
}

// ---- r8 fallback kernels --------------------------------------------------

__global__ __launch_bounds__(256) void fused_prep(XcvtTab xt, WTab wt,
                                                  __bf16* __restrict__ XbT,
                                                  __bf16* __restrict__ WtT,
                                                  int* __restrict__ cursor,
                                                  float* __restrict__ poolh,
                                                  int* __restrict__ segc) {
    __shared__ __align__(16) char smemraw[16384];
    const int b = blockIdx.x;
    if (b < X4) {
        convert_x_core(xt, XbT, smemraw, b);
    } else if (b < X4 + WB) {
        convert_w_core(wt, WtT, b - X4);
    } else {
        const int t = threadIdx.x;
        cursor[t] = 0;
        for (int k = t; k < 3 * BB * CC; k += 256) poolh[k] = 0.f;
        if (t < 32) segc[t] = 0;
    }
}

__global__ __launch_bounds__(256) void part_seg(SrcTab st, int* __restrict__ cursor,
                                                int2* __restrict__ stage, int total, int nch,
                                                const int* s0, const int* s1, const int* s2,
                                                int* __restrict__ segc) {
    const int b = blockIdx.x;
    if (b < nch) partition_core(st, cursor, stage, total, b);
    else         seg_core(s0, s1, s2, segc, b - nch);
}

__global__ __launch_bounds__(256) void gemm_pool(GemmTab tab, int njobs,
                                                 const __bf16* __restrict__ WtT,
                                                 const __bf16* __restrict__ XbT,
                                                 __bf16* __restrict__ T,
                                                 const __bf16* __restrict__ accb,
                                                 const int* __restrict__ seg,
                                                 float* __restrict__ poolh, int n) {
    __shared__ __align__(16) char smemraw[16384];
    if ((int)blockIdx.z < njobs) {
        gemm_core(tab.j[blockIdx.z], WtT, XbT, T, smemraw, blockIdx.x, blockIdx.y);
    } else {
        int flat = blockIdx.y * gridDim.x + blockIdx.x;
        if (flat < (n + 63) / 64) pool_core(accb, seg, poolh, n, flat);
    }
}

__global__ __launch_bounds__(256) void pool_k(const __bf16* __restrict__ acc,
                                              const int* __restrict__ seg,
                                              float* __restrict__ poolh, int n) {
    pool_core(acc, seg, poolh, n, blockIdx.x);
}

__global__ __launch_bounds__(256) void bin_scatter_k(const int2* __restrict__ stage,
                                                     const int* __restrict__ cnts,
                                                     int* __restrict__ rstart,
                                                     int2* __restrict__ epair) {
    __shared__ __align__(16) char smemraw[16384];
    scatter_core(stage, cnts, rstart, epair, smemraw, blockIdx.x);
}

__global__ void convert_w_old(WTab wt, __bf16* __restrict__ Wt) {
    int b = blockIdx.x;
    int w = b >> 8, n = b & 255;
    int k = threadIdx.x;
    Wt[((size_t)w * 256 + n) * 256 + k] = (__bf16)wt.w[w][k * 256 + n];
}

__global__ __launch_bounds__(256) void gemm_level(GemmTab tab,
                                                  const __bf16* __restrict__ WtAll,
                                                  __bf16* __restrict__ T) {
    const GemmJob job = tab.j[blockIdx.z];
    const int row0 = blockIdx.x * 128;
    if (row0 >= job.M) return;
    const int M = job.M;
    const float* __restrict__ X = job.X;
    const __bf16* __restrict__ Wt = WtAll + (size_t)job.wIdx * CC * CC;

    __shared__ __bf16 Als[4096];
    __shared__ __bf16 Bls[4096];
    const int t = threadIdx.x;
    const int col0 = blockIdx.y * 128;
    const int lane = t & 63, wave = t >> 6;
    const int q = lane >> 4, lm = lane & 15;
    const int wm = (wave & 1) * 64, wn = (wave >> 1) * 64;

    f32x4 acc[4][4];
    const f32x4 z = {0.f, 0.f, 0.f, 0.f};
#pragma unroll
    for (int i = 0; i < 4; ++i)
#pragma unroll
        for (int j = 0; j < 4; ++j) acc[i][j] = z;

    const int g0 = t >> 7, ms = t & 127;
    int arow = row0 + ms; if (arow > M - 1) arow = M - 1;
    const float*  ap = X  + (size_t)arow * CC;
    const __bf16* bp = Wt + (size_t)(col0 + ms) * CC;

    for (int kk = 0; kk < CC; kk += 32) {
#pragma unroll
        for (int s = 0; s < 2; ++s) {
            int g = g0 + s * 2;
            float4 f0 = *(const float4*)(ap + kk + g * 8);
            float4 f1 = *(const float4*)(ap + kk + g * 8 + 4);
            bf16x8 pk;
            pk[0] = (__bf16)f0.x; pk[1] = (__bf16)f0.y; pk[2] = (__bf16)f0.z; pk[3] = (__bf16)f0.w;
            pk[4] = (__bf16)f1.x; pk[5] = (__bf16)f1.y; pk[6] = (__bf16)f1.z; pk[7] = (__bf16)f1.w;
            *(bf16x8*)&Als[(g * 128 + ms) * 8] = pk;
            *(bf16x8*)&Bls[(g * 128 + ms) * 8] = *(const bf16x8*)(bp + kk + g * 8);
        }
        __syncthreads();
        bf16x8 af[4], bfr[4];
#pragma unroll
        for (int i = 0; i < 4; ++i)
            af[i] = *(bf16x8*)&Als[(q * 128 + wm + 16 * i + lm) * 8];
#pragma unroll
        for (int j = 0; j < 4; ++j)
            bfr[j] = *(bf16x8*)&Bls[(q * 128 + wn + 16 * j + lm) * 8];
#pragma unroll
        for (int i = 0; i < 4; ++i)
#pragma unroll
            for (int j = 0; j < 4; ++j)
                acc[i][j] = __builtin_amdgcn_mfma_f32_16x16x32_bf16(af[i], bfr[j], acc[i][j], 0, 0, 0);
        __syncthreads();
    }
#pragma unroll
    for (int i = 0; i < 4; ++i) {
        int gr0 = row0 + wm + 16 * i + q * 4;
#pragma unroll
        for (int r = 0; r < 4; ++r) {
            int grow = gr0 + r;
            if (grow < M) {
                __bf16* dst = T + (size_t)(job.rowBase + grow) * CC + col0 + wn + lm;
#pragma unroll
                for (int j = 0; j < 4; ++j) dst[16 * j] = (__bf16)acc[i][j][r];
            }
        }
    }
}

__global__ __launch_bounds__(256) void spmm_level(const int2* __restrict__ epair,
                                                  const int* __restrict__ rstart,
                                                  const __bf16* __restrict__ T,
                                                  __bf16* __restrict__ acc,
                                                  int Kb, int S, int nrows) {
    spmm_group(epair, rstart, T, acc, Kb, S, nrows, blockIdx.x);
}

__global__ __launch_bounds__(64) void final_head(const float* __restrict__ ph0,
                                                 const float* __restrict__ ph1,
                                                 const float* __restrict__ ph2,
                                                 const int* __restrict__ c0,
                                                 const int* __restrict__ c1,
                                                 const int* __restrict__ c2,
                                                 const float* __restrict__ W0,
                                                 const float* __restrict__ W1,
                                                 const float* __restrict__ W2,
                                                 const float* __restrict__ b0,
                                                 const float* __restrict__ b1,
                                                 const float* __restrict__ b2,
                                                 float* __restrict__ out) {
    int s = blockIdx.x, o = threadIdx.x;
    float inv0 = 1.f / fmaxf((float)c0[s], 1.f);
    float inv1 = 1.f / fmaxf((float)c1[s], 1.f);
    float inv2 = 1.f / fmaxf((float)c2[s], 1.f);
    float a0 = 0.f, a1 = 0.f, a2 = 0.f;
    for (int k = 0; k < CC; ++k) {
        a0 += ph0[s * CC + k] * W0[k * OUTD + o];
        a1 += ph1[s * CC + k] * W1[k * OUTD + o];
        a2 += ph2[s * CC + k] * W2[k * OUTD + o];
    }
    out[s * OUTD + o] = (a0 * inv0 + b0[o] + a1 * inv1 + b1[o] + a2 * inv2 + b2[o]) * (1.f / 3.f);
}

// ---------------------------------------------------------------------------
extern "C" void kernel_launch(void* const* d_in, const int* in_sizes, int n_in,
                              void* d_out, int out_size, void* d_ws, size_t ws_size,
                              hipStream_t stream) {
    const float* x0 = (const float*)d_in[0];
    const float* x1 = (const float*)d_in[1];
    const float* x2 = (const float*)d_in[2];
    const int* belong0 = (const int*)d_in[27];
    const int* belong1 = (const int*)d_in[28];
    const int* belong2 = (const int*)d_in[29];

    // ---- overlap (big) layout ----
    char* w = (char*)d_ws;
    __bf16* Ta   = (__bf16*)w;  w += (size_t)100000 * CC * 2;  // 51.2 MB (L0:80K, L2:100K rows)
    __bf16* Tb   = (__bf16*)w;  w += (size_t)120000 * CC * 2;  // 61.44 MB (L1)
    __bf16* accA = (__bf16*)w;  w += (size_t)40000 * CC * 2;   // 20.48 MB (spmm L0/L2 out)
    __bf16* accB = (__bf16*)w;  w += (size_t)NN1 * CC * 2;     // 30.72 MB (spmm L1 out)
    __bf16* WtB  = (__bf16*)w;  w += (size_t)7 * CC * CC * 2;
    int2*   epairB = (int2*)w;  w += (size_t)ECAP * 8;
    int*  curB   = (int*)w;     w += NBUK * 4;                 // zero-region start
    float* phB   = (float*)w;   w += 3 * BB * CC * 4;
    int*  segB   = (int*)w;     w += 32 * 4;                   // zero-region end
    int*  rstB   = (int*)w;     w += (size_t)CTOT * 4;
    __bf16* XbTB = (__bf16*)w;  w += (size_t)XTTOT * 4096 * 16;
    size_t required_big = (size_t)(w - (char*)d_ws);
    // stage aliases accA+accB (25.2 MB <= 51.2): written L1-2, read L2; acc* first written L3+
    int2* stageB = (int2*)accA;

    // ---- r8 fallback layout ----
    w = (char*)d_ws;
    __bf16* T    = (__bf16*)w;  w += (size_t)120000 * CC * 2;
    __bf16* accb = (__bf16*)w;  w += (size_t)NN1 * CC * 2;
    __bf16* Wt   = (__bf16*)w;  w += (size_t)7 * CC * CC * 2;
    int2*   epair= (int2*)w;    w += (size_t)ECAP * 8;
    int*  bucketCursor = (int*)w; w += NBUK * 4;
    float*  poolh= (float*)w;   w += 3 * BB * CC * 4;
    int*    segc = (int*)w;     w += 32 * 4;
    int*    rstart=(int*)w;     w += (size_t)CTOT * 4;
    __bf16* XbT  = (__bf16*)w;  w += (size_t)XTTOT * 4096 * 16;
    size_t required_new = (size_t)(w - (char*)d_ws);
    int2* stage = (int2*)accb;

    const bool use_big  = (ws_size >= required_big);
    const bool use_glds = (ws_size >= required_new);

    // ---- source table ----
    const int bases[8] = {15, 3, 9, 21, 18, 6, 12, 24};
    const int kbase[8] = {KB_L0, KB_L0, KB_L1, KB_L1, KB_L1, KB_L1, KB_L2, KB_L2};
    const int mulS [8] = {2, 2, 3, 3, 3, 3, 2, 2};
    const int slot [8] = {0, 1, 0, 1, 1, 2, 0, 1};
    const int tbase[8] = {0, 20000, 0, 20000, 20000, 80000, 0, 60000};
    SrcTab st;
    int run = 0;
    for (int s = 0; s < 8; ++s) {
        st.rows[s] = (const int*)d_in[bases[s]];
        st.cols[s] = (const int*)d_in[bases[s] + 1];
        st.vals[s] = (const float*)d_in[bases[s] + 2];
        st.kbase[s] = kbase[s]; st.mulS[s] = mulS[s];
        st.slot[s] = slot[s];   st.tbase[s] = tbase[s];
        st.pre[s] = run;
        run += in_sizes[bases[s]];
    }
    st.pre[8] = run;
    const int total = run;
    const int nch = (total + ACHUNK - 1) / ACHUNK;
    const int nsegb = (NN1 + 255) / 256;

    WTab wt;
    for (int i = 0; i < 7; ++i) wt.w[i] = (const float*)d_in[30 + i];

    XcvtTab xt;
    xt.src[0] = x0; xt.src[1] = x1; xt.src[2] = x2;
    xt.tstart[0] = XT0; xt.tstart[1] = XT1; xt.tstart[2] = XT2; xt.tstart[3] = XTTOT;
    xt.nrows[0] = NN0; xt.nrows[1] = NN1; xt.nrows[2] = NN2;

    if (use_big) {
        // 0: zero cursor/poolh/segc
        zero_kernel<<<8, 256, 0, stream>>>((float4*)curB,
                                           (NBUK * 4 + 3 * BB * CC * 4 + 128) / 16);
        // 1: partition | seg | convert_w | convert_x
        mega_prep<<<nch + nsegb + WB + X4, 256, 0, stream>>>(xt, wt, st, XbTB, WtB,
                                                             curB, stageB, total, nch,
                                                             belong0, belong1, belong2,
                                                             segB, nsegb);
        // 2: gemm L0 -> Ta | scatter
        {
            GemmTab g;
            g.j[0] = {x0, XT0, 0, 0, NN0};
            g.j[1] = {x1, XT1, 1, 20000, NN1};
            gemm_scatter<<<dim3(GXB, 2, 3), 256, 0, stream>>>(g, 2, WtB, XbTB, Ta,
                                                              stageB, curB, rstB, epairB);
        }
        // 3: gemm L1 -> Tb | spmm L0 (Ta->accA)
        {
            GemmTab g;
            g.j[0] = {x0, XT0, 2, 0, NN0};
            g.j[1] = {x1, XT1, 3, 20000, NN1};
            g.j[2] = {x2, XT2, 4, 80000, NN2};
            gemm1_spmm0<<<3 * 2 * GXB + (NN0 + 3) / 4, 256, 0, stream>>>(
                g, WtB, XbTB, Tb, epairB, rstB, Ta, accA);
        }
        // 4: gemm L2 -> Ta | pool L0 (accA) | spmm L1 (Tb->accB)
        {
            GemmTab g;
            g.j[0] = {x1, XT1, 5, 0, NN1};
            g.j[1] = {x2, XT2, 6, 60000, NN2};
            gemm2_pool0_spmm1<<<2 * 2 * GXB + (NN0 + 63) / 64 + (NN1 + 3) / 4, 256, 0, stream>>>(
                g, WtB, XbTB, Ta, accA, belong0, phB, epairB, rstB, Tb, accB);
        }
        // 5: pool L1 (accB) | spmm L2 (Ta->accA)
        pool1_spmm2<<<(NN1 + 63) / 64 + (NN2 + 3) / 4, 256, 0, stream>>>(
            accB, belong1, phB + BB * CC, epairB, rstB, Ta, accA);
        // 6: pool L2
        pool_k<<<(NN2 + 63) / 64, 256, 0, stream>>>(accA, belong2, phB + 2 * BB * CC, NN2);
        // 7: final
        final_head<<<BB, 64, 0, stream>>>(phB, phB + BB * CC, phB + 2 * BB * CC,
                                          segB, segB + 8, segB + 16,
                                          (const float*)d_in[37], (const float*)d_in[38],
                                          (const float*)d_in[39], (const float*)d_in[40],
                                          (const float*)d_in[41], (const float*)d_in[42],
                                          (float*)d_out);
    } else if (use_glds) {
        // ---- exact round-8 sequence ----
        fused_prep<<<X4 + WB + 1, 256, 0, stream>>>(xt, wt, XbT, Wt,
                                                    bucketCursor, poolh, segc);
        part_seg<<<nch + nsegb, 256, 0, stream>>>(st, bucketCursor, stage, total, nch,
                                                  belong0, belong1, belong2, segc);
        {
            GemmTab g;
            g.j[0] = {x0, XT0, 0, 0, NN0};
            g.j[1] = {x1, XT1, 1, 20000, NN1};
            gemm_scatter<<<dim3(GXB, 2, 3), 256, 0, stream>>>(g, 2, Wt, XbT, T,
                                                              stage, bucketCursor, rstart, epair);
        }
        spmm_level<<<(NN0 + 3) / 4, 256, 0, stream>>>(epair, rstart, T, accb, KB_L0, 2, NN0);
        {
            GemmTab g;
            g.j[0] = {x0, XT0, 2, 0, NN0};
            g.j[1] = {x1, XT1, 3, 20000, NN1};
            g.j[2] = {x2, XT2, 4, 80000, NN2};
            gemm_pool<<<dim3(GXB, 2, 4), 256, 0, stream>>>(g, 3, Wt, XbT, T,
                                                           accb, belong0, poolh, NN0);
        }
        spmm_level<<<(NN1 + 3) / 4, 256, 0, stream>>>(epair, rstart, T, accb, KB_L1, 3, NN1);
        {
            GemmTab g;
            g.j[0] = {x1, XT1, 5, 0, NN1};
            g.j[1] = {x2, XT2, 6, 60000, NN2};
            gemm_pool<<<dim3(GXB, 2, 3), 256, 0, stream>>>(g, 2, Wt, XbT, T,
                                                           accb, belong1, poolh + BB * CC, NN1);
        }
        spmm_level<<<(NN2 + 3) / 4, 256, 0, stream>>>(epair, rstart, T, accb, KB_L2, 2, NN2);
        pool_k<<<(NN2 + 63) / 64, 256, 0, stream>>>(accb, belong2, poolh + 2 * BB * CC, NN2);
        final_head<<<BB, 64, 0, stream>>>(poolh, poolh + BB * CC, poolh + 2 * BB * CC,
                                          segc, segc + 8, segc + 16,
                                          (const float*)d_in[37], (const float*)d_in[38],
                                          (const float*)d_in[39], (const float*)d_in[40],
                                          (const float*)d_in[41], (const float*)d_in[42],
                                          (float*)d_out);
    } else {
        // ---- minimal old path (fp32-X GEMM, separate launches) ----
        zero_kernel<<<8, 256, 0, stream>>>((float4*)bucketCursor,
                                           (NBUK * 4 + 3 * BB * CC * 4 + 128) / 16);
        part_seg<<<nch + nsegb, 256, 0, stream>>>(st, bucketCursor, stage, total, nch,
                                                  belong0, belong1, belong2, segc);
        convert_w_old<<<7 * 256, 256, 0, stream>>>(wt, Wt);
        bin_scatter_k<<<NBUK, 256, 0, stream>>>(stage, bucketCursor, rstart, epair);
        {
            GemmTab g;
            g.j[0] = {x0, XT0, 0, 0, NN0};
            g.j[1] = {x1, XT1, 1, 20000, NN1};
            gemm_level<<<dim3(GXB, 2, 2), 256, 0, stream>>>(g, Wt, T);
            spmm_level<<<(NN0 + 3) / 4, 256, 0, stream>>>(epair, rstart, T, accb, KB_L0, 2, NN0);
            pool_k<<<(NN0 + 63) / 64, 256, 0, stream>>>(accb, belong0, poolh, NN0);
        }
        {
            GemmTab g;
            g.j[0] = {x0, XT0, 2, 0, NN0};
            g.j[1] = {x1, XT1, 3, 20000, NN1};
            g.j[2] = {x2, XT2, 4, 80000, NN2};
            gemm_level<<<dim3(GXB, 2, 3), 256, 0, stream>>>(g, Wt, T);
            spmm_level<<<(NN1 + 3) / 4, 256, 0, stream>>>(epair, rstart, T, accb, KB_L1, 3, NN1);
            pool_k<<<(NN1 + 63) / 64, 256, 0, stream>>>(accb, belong1, poolh + BB * CC, NN1);
        }
        {
            GemmTab g;
            g.j[0] = {x1, XT1, 5, 0, NN1};
            g.j[1] = {x2, XT2, 6, 60000, NN2};
            gemm_level<<<dim3(GXB, 2, 2), 256, 0, stream>>>(g, Wt, T);
            spmm_level<<<(NN2 + 3) / 4, 256, 0, stream>>>(epair, rstart, T, accb, KB_L2, 2, NN2);
            pool_k<<<(NN2 + 63) / 64, 256, 0, stream>>>(accb, belong2, poolh + 2 * BB * CC, NN2);
        }
        final_head<<<BB, 64, 0, stream>>>(poolh, poolh + BB * CC, poolh + 2 * BB * CC,
                                          segc, segc + 8, segc + 16,
                                          (const float*)d_in[37], (const float*)d_in[38],
                                          (const float*)d_in[39], (const float*)d_in[40],
                                          (const float*)d_in[41], (const float*)d_in[42],
                                          (float*)d_out);
    }
}